// Round 4
// baseline (1005.537 us; speedup 1.0000x reference)
//
#include <hip/hip_runtime.h>

// Problem constants
#define N_   1024
#define R_   100
#define D_   256
#define T_   14
#define H_   8
#define DH_  32
#define MM_  600
#define OBJ_ 36

typedef _Float16 f16;
typedef __attribute__((ext_vector_type(8))) _Float16 f16x8;
typedef __attribute__((ext_vector_type(4))) _Float16 f16x4v;
typedef __attribute__((ext_vector_type(4))) float f32x4;

// fp32 -> (hi, lo) fp16 split: x ≈ hi + lo with ~22-bit combined mantissa
__device__ __forceinline__ void f2h_split(float x, f16& hi, f16& lo) {
  hi = (_Float16)x;
  lo = (_Float16)(x - (float)hi);
}

// async 16B global->LDS
#define GL16(gp, lp) __builtin_amdgcn_global_load_lds( \
    (const __attribute__((address_space(1))) void*)(gp), \
    (__attribute__((address_space(3))) void*)(lp), 16, 0, 0)

// ---------------------------------------------------------------------------
__device__ __forceinline__ float plin_f(const float* __restrict__ w,
                                        const float* __restrict__ cs, float x) {
  float xc = fminf(fmaxf(x, 0.f), 1.f);
  float y  = 16.f * xc;
  float fy = floorf(y);
  int   i  = (int)fy;              // 0..16
  float f  = y - fy;
  int   ip = i + 1; if (ip > 16) ip = 16;
  return cs[i] + f * w[ip];
}

// ---------------------------------------------------------------------------
__global__ void prep_plin(const float* __restrict__ pw, float* __restrict__ plw,
                          float* __restrict__ plc) {
  int p = threadIdx.x;
  if (p < 8) {
    float w[17];
    float sum = 0.f;
    w[0] = 0.f;
    for (int k = 1; k < 17; ++k) { w[k] = fabsf(pw[p*17 + k]); sum += w[k]; }
    float inv = 1.f / sum;
    float c = 0.f;
    for (int k = 0; k < 17; ++k) {
      float wk = w[k] * inv;
      c += wk;
      plw[p*17 + k] = wk;
      plc[p*17 + k] = c;
    }
  }
}

// ---------------------------------------------------------------------------
__global__ void fuse_c(const float* __restrict__ in_w, const float* __restrict__ in_b,
                       const float* __restrict__ bq, const float* __restrict__ bk,
                       const float* __restrict__ bv, float* __restrict__ c) {
  int i = blockIdx.x * blockDim.x + threadIdx.x;
  if (i < 768) {
    const float* bsel = (i < 256) ? bq : ((i < 512) ? bk : bv);
    float acc = in_b[i];
    for (int o = 0; o < 256; ++o) acc += in_w[(size_t)i*256 + o] * bsel[o];
    c[i] = acc;
  }
}

__global__ __launch_bounds__(256) void fuse_A(const float* __restrict__ in_w,
    const float* __restrict__ Wq, const float* __restrict__ Wk,
    const float* __restrict__ Wv, f16* __restrict__ Ahi, f16* __restrict__ Alo) {
  int i = blockIdx.x;        // 0..767
  int j = threadIdx.x;       // 0..255
  const float* Wsel = (i < 256) ? Wq : ((i < 512) ? Wk : Wv);
  __shared__ float row[256];
  row[j] = in_w[(size_t)i*256 + j];
  __syncthreads();
  float acc = 0.f;
  for (int o = 0; o < 256; ++o) acc += row[o] * Wsel[(size_t)o*256 + j];
  f16 h, l; f2h_split(acc, h, l);
  Ahi[(size_t)i*256 + j] = h;
  Alo[(size_t)i*256 + j] = l;
}

__global__ __launch_bounds__(256) void split_vec(const float* __restrict__ in,
    f16* __restrict__ hi, f16* __restrict__ lo, int n4) {
  int i = blockIdx.x * blockDim.x + threadIdx.x;
  if (i < n4) {
    float4 v = ((const float4*)in)[i];
    union { f16 h[4]; ushort4 u; } H, L;
    f2h_split(v.x, H.h[0], L.h[0]);
    f2h_split(v.y, H.h[1], L.h[1]);
    f2h_split(v.z, H.h[2], L.h[2]);
    f2h_split(v.w, H.h[3], L.h[3]);
    ((ushort4*)hi)[i] = H.u;
    ((ushort4*)lo)[i] = L.u;
  }
}

// 600x256 weight -> split fp16 padded to 640x256 (zero rows beyond 600)
__global__ __launch_bounds__(256) void conv_w600(const float* __restrict__ w,
    f16* __restrict__ hi, f16* __restrict__ lo) {
  int o = blockIdx.x;        // 0..639
  int j = threadIdx.x;       // 0..255
  f16 h = (f16)0.f, l = (f16)0.f;
  if (o < 600) f2h_split(w[(size_t)o*256 + j], h, l);
  hi[(size_t)o*256 + j] = h;
  lo[(size_t)o*256 + j] = l;
}

// q_emb mean-pool -> split fp16 (one block per n)
__global__ __launch_bounds__(256) void pool_split(const float* __restrict__ q_emb,
    f16* __restrict__ qph, f16* __restrict__ qpl) {
  int n = blockIdx.x, tid = threadIdx.x;
  float s = 0.f;
  for (int t = 0; t < 14; ++t) s += q_emb[((size_t)n*14 + t)*256 + tid];
  s *= (1.f/14.f);
  f16 h, l; f2h_split(s, h, l);
  qph[(size_t)n*256 + tid] = h;
  qpl[(size_t)n*256 + tid] = l;
}

// ---------------------------------------------------------------------------
// split-fp16 MFMA GEMM (fp32-accurate): C[m][o] = sum_k X[m][k]*W[o][k] + bias[o]
template<bool BOUND>
__global__ __launch_bounds__(256) void gemm_f16s(
    const f16* __restrict__ Xhi, const f16* __restrict__ Xlo,
    const f16* __restrict__ Whi, const f16* __restrict__ Wlo,
    const float* __restrict__ bias, float* __restrict__ C, int Oreal) {
  __shared__ f16 XsH[128 * 32];
  __shared__ f16 XsL[128 * 32];
  __shared__ f16 WsH[128 * 32];
  __shared__ f16 WsL[128 * 32];
  const int tid  = threadIdx.x;
  const int wave = tid >> 6, lane = tid & 63;
  const int bm = blockIdx.x * 128, bn = blockIdx.y * 128;
  const int wm = (wave & 1) * 64, wn = (wave >> 1) * 64;
  const int col = lane & 15, quad = lane >> 4;

  const int s = wave * 64 + lane;
  const int r0 = s >> 2,         cseg = (s & 3) * 8;
  const int r1 = (s + 256) >> 2;
  const size_t o0 = (size_t)(bm + r0) * 256 + cseg;
  const size_t o1 = (size_t)(bm + r1) * 256 + cseg;
  const size_t p0 = (size_t)(bn + r0) * 256 + cseg;
  const size_t p1 = (size_t)(bn + r1) * 256 + cseg;
  char* XHB = (char*)XsH + wave * 1024;
  char* XLB = (char*)XsL + wave * 1024;
  char* WHB = (char*)WsH + wave * 1024;
  char* WLB = (char*)WsL + wave * 1024;

  f32x4 acc[4][4] = {};

  for (int k0 = 0; k0 < 256; k0 += 32) {
    GL16(Xhi + o0 + k0, XHB);
    GL16(Xhi + o1 + k0, XHB + 4096);
    GL16(Xlo + o0 + k0, XLB);
    GL16(Xlo + o1 + k0, XLB + 4096);
    GL16(Whi + p0 + k0, WHB);
    GL16(Whi + p1 + k0, WHB + 4096);
    GL16(Wlo + p0 + k0, WLB);
    GL16(Wlo + p1 + k0, WLB + 4096);
    __syncthreads();

    f16x8 ah[4], al[4], bh[4], bl[4];
#pragma unroll
    for (int i = 0; i < 4; ++i) {
      int ro = (wm + i*16 + col) * 32 + quad * 8;
      ah[i] = *(const f16x8*)(XsH + ro);
      al[i] = *(const f16x8*)(XsL + ro);
    }
#pragma unroll
    for (int j = 0; j < 4; ++j) {
      int ro = (wn + j*16 + col) * 32 + quad * 8;
      bh[j] = *(const f16x8*)(WsH + ro);
      bl[j] = *(const f16x8*)(WsL + ro);
    }
#pragma unroll
    for (int i = 0; i < 4; ++i)
#pragma unroll
      for (int j = 0; j < 4; ++j) {
        acc[i][j] = __builtin_amdgcn_mfma_f32_16x16x32_f16(al[i], bh[j], acc[i][j], 0, 0, 0);
        acc[i][j] = __builtin_amdgcn_mfma_f32_16x16x32_f16(ah[i], bl[j], acc[i][j], 0, 0, 0);
        acc[i][j] = __builtin_amdgcn_mfma_f32_16x16x32_f16(ah[i], bh[j], acc[i][j], 0, 0, 0);
      }
    __syncthreads();
  }

#pragma unroll
  for (int j = 0; j < 4; ++j) {
    int o = bn + wn + j*16 + col;
    if (BOUND && o >= Oreal) continue;
    float bo = bias[o];
#pragma unroll
    for (int i = 0; i < 4; ++i) {
#pragma unroll
      for (int r = 0; r < 4; ++r) {
        int m = bm + wm + i*16 + quad*4 + r;
        C[(size_t)m * Oreal + o] = acc[i][j][r] + bo;
      }
    }
  }
}

// ---------------------------------------------------------------------------
// l0 GEMM with FUSED MLB partial reduction v2.
// Epilogue avoids the R3 costs: x1 is staged to LDS (3 images x 128 cols,
// coalesced) instead of 64 scattered per-lane global loads, and the 16-lane
// reduction uses a wave-private LDS transpose (16 ds_write_b64 + 16 ds_read
// + 8 shuffles) instead of 128 ds_swizzle butterfly ops.
__global__ __launch_bounds__(256) void gemm_l0_mlb(
    const f16* __restrict__ Xhi, const f16* __restrict__ Xlo,
    const f16* __restrict__ Whi, const f16* __restrict__ Wlo,
    const float* __restrict__ bias, const float* __restrict__ x1,
    const float* __restrict__ lo_w, float2* __restrict__ part) {
  __shared__ f16 XsH[128 * 32];
  __shared__ f16 XsL[128 * 32];
  __shared__ f16 WsH[128 * 32];
  __shared__ f16 WsL[128 * 32];
  __shared__ float  x1s[3][128];        // x1 slab: 3 images x block cols
  __shared__ float2 red_s[4][16][17];   // wave-private transpose-reduce pad+1
  const int tid  = threadIdx.x;
  const int wave = tid >> 6, lane = tid & 63;
  const int bm = blockIdx.x * 128, bn = blockIdx.y * 128;
  const int wm = (wave & 1) * 64, wn = (wave >> 1) * 64;
  const int col = lane & 15, quad = lane >> 4;

  const int s = wave * 64 + lane;
  const int r0 = s >> 2,         cseg = (s & 3) * 8;
  const int r1 = (s + 256) >> 2;
  const size_t o0 = (size_t)(bm + r0) * 256 + cseg;
  const size_t o1 = (size_t)(bm + r1) * 256 + cseg;
  const size_t p0 = (size_t)(bn + r0) * 256 + cseg;
  const size_t p1 = (size_t)(bn + r1) * 256 + cseg;
  char* XHB = (char*)XsH + wave * 1024;
  char* XLB = (char*)XsL + wave * 1024;
  char* WHB = (char*)WsH + wave * 1024;
  char* WLB = (char*)WsL + wave * 1024;

  f32x4 acc[4][4] = {};

  for (int k0 = 0; k0 < 256; k0 += 32) {
    GL16(Xhi + o0 + k0, XHB);
    GL16(Xhi + o1 + k0, XHB + 4096);
    GL16(Xlo + o0 + k0, XLB);
    GL16(Xlo + o1 + k0, XLB + 4096);
    GL16(Whi + p0 + k0, WHB);
    GL16(Whi + p1 + k0, WHB + 4096);
    GL16(Wlo + p0 + k0, WLB);
    GL16(Wlo + p1 + k0, WLB + 4096);
    __syncthreads();

    f16x8 ah[4], al[4], bh[4], bl[4];
#pragma unroll
    for (int i = 0; i < 4; ++i) {
      int ro = (wm + i*16 + col) * 32 + quad * 8;
      ah[i] = *(const f16x8*)(XsH + ro);
      al[i] = *(const f16x8*)(XsL + ro);
    }
#pragma unroll
    for (int j = 0; j < 4; ++j) {
      int ro = (wn + j*16 + col) * 32 + quad * 8;
      bh[j] = *(const f16x8*)(WsH + ro);
      bl[j] = *(const f16x8*)(WsL + ro);
    }
#pragma unroll
    for (int i = 0; i < 4; ++i)
#pragma unroll
      for (int j = 0; j < 4; ++j) {
        acc[i][j] = __builtin_amdgcn_mfma_f32_16x16x32_f16(al[i], bh[j], acc[i][j], 0, 0, 0);
        acc[i][j] = __builtin_amdgcn_mfma_f32_16x16x32_f16(ah[i], bl[j], acc[i][j], 0, 0, 0);
        acc[i][j] = __builtin_amdgcn_mfma_f32_16x16x32_f16(ah[i], bh[j], acc[i][j], 0, 0, 0);
      }
    __syncthreads();
  }

  // ---- fused MLB epilogue v2 ----
  const int Mtot = (int)gridDim.x * 128;     // == chunk rows (NC*100 padded)
  const int i0 = bm / 100;
  // stage x1 slab (coalesced; zero-fill outside valid range)
  for (int t = tid; t < 384; t += 256) {
    int di = t >> 7, c = t & 127;
    int img = i0 + di;
    int o = bn + c;
    float v = 0.f;
    if (img * 100 < Mtot && o < 600) v = x1[(size_t)img * 600 + o];
    x1s[di][c] = v;
  }
  __syncthreads();

  float bo4[4], lw4[4];
#pragma unroll
  for (int j = 0; j < 4; ++j) {
    int o = bn + wn + j*16 + col;
    bo4[j] = (o < 600) ? bias[o] : 0.f;
    lw4[j] = (o < 600) ? lo_w[o] : 0.f;
  }

#pragma unroll
  for (int i = 0; i < 4; ++i) {
    // per-lane partials for this i-pass (rows wm + i*16 + quad*4 + rr)
#pragma unroll
    for (int rr = 0; rr < 4; ++rr) {
      int m = bm + wm + i*16 + quad*4 + rr;
      int di = m / 100 - i0;                 // 0..2 (compiler const-div)
      float ss = 0.f, dt = 0.f;
#pragma unroll
      for (int j = 0; j < 4; ++j) {
        int oc = wn + j*16 + col;
        if (bn + oc < 600) {
          float v = (acc[i][j][rr] + bo4[j]) * x1s[di][oc];
          float rt = (v >= 0.f) ? sqrtf(v) : -sqrtf(-v);
          ss += rt * rt;
          dt += rt * lw4[j];
        }
      }
      float2 pv; pv.x = ss; pv.y = dt;
      red_s[wave][quad*4 + rr][col] = pv;    // wave-private, in-order DS
    }
    // transpose-reduce: 4 lanes per row, then 2 shuffles
    int lr = lane >> 2, seg = lane & 3;
    float2 a0 = red_s[wave][lr][seg*4 + 0];
    float2 a1 = red_s[wave][lr][seg*4 + 1];
    float2 a2 = red_s[wave][lr][seg*4 + 2];
    float2 a3 = red_s[wave][lr][seg*4 + 3];
    float ss = a0.x + a1.x + a2.x + a3.x;
    float dt = a0.y + a1.y + a2.y + a3.y;
    ss += __shfl_xor(ss, 1, 64); dt += __shfl_xor(dt, 1, 64);
    ss += __shfl_xor(ss, 2, 64); dt += __shfl_xor(dt, 2, 64);
    if (seg == 0) {
      int m = bm + wm + i*16 + lr;
      float2 pv; pv.x = ss; pv.y = dt;
      part[(size_t)m * 10 + blockIdx.y * 2 + (wn >> 6)] = pv;
    }
  }
}

// combine 10 partials per row -> normalize -> sigmoid -> scores
__global__ __launch_bounds__(256) void mlb_reduce(const float2* __restrict__ part,
    const float* __restrict__ lo_b, float* __restrict__ out, int M) {
  int m = blockIdx.x * 256 + threadIdx.x;
  if (m < M) {
    const float2* p = part + (size_t)m * 10;
    float ss = 0.f, dt = 0.f;
#pragma unroll
    for (int t = 0; t < 10; ++t) { float2 v = p[t]; ss += v.x; dt += v.y; }
    float sc = dt / fmaxf(sqrtf(ss), 1e-12f) + lo_b[0];
    out[m] = 1.f / (1.f + __expf(-sc));
  }
}

// ---------------------------------------------------------------------------
// out-proj GEMM + fused LayerNorm: tile 128 rows x FULL 256 cols per block.
// inter = LN(ao @ out_w^T + out_b); writes split f16 directly.
__global__ __launch_bounds__(256) void gemm2_ln(
    const f16* __restrict__ Xhi, const f16* __restrict__ Xlo,
    const f16* __restrict__ Whi, const f16* __restrict__ Wlo,
    const float* __restrict__ bias, const float* __restrict__ g,
    const float* __restrict__ b, f16* __restrict__ ohi, f16* __restrict__ olo) {
  __shared__ f16 XsH[128 * 32];
  __shared__ f16 XsL[128 * 32];
  __shared__ f16 WsH[256 * 32];
  __shared__ f16 WsL[256 * 32];
  __shared__ float gbb[768];   // g | b | bias
  const int tid  = threadIdx.x;
  const int wave = tid >> 6, lane = tid & 63;
  const int bm = blockIdx.x * 128;
  const int wm = wave * 32;
  const int col16 = lane & 15, quad = lane >> 4;

  for (int i = tid; i < 768; i += 256)
    gbb[i] = (i < 256) ? g[i] : ((i < 512) ? b[i - 256] : bias[i - 512]);

  const int s = wave * 64 + lane;
  const int rx0 = s >> 2, cseg = (s & 3) * 8;
  const int rx1 = (s + 256) >> 2;
  const size_t o0 = (size_t)(bm + rx0) * 256 + cseg;
  const size_t o1 = (size_t)(bm + rx1) * 256 + cseg;
  char* XHB = (char*)XsH + wave * 1024;
  char* XLB = (char*)XsL + wave * 1024;

  f32x4 acc[2][16] = {};

  for (int k0 = 0; k0 < 256; k0 += 32) {
    GL16(Xhi + o0 + k0, XHB);
    GL16(Xhi + o1 + k0, XHB + 4096);
    GL16(Xlo + o0 + k0, XLB);
    GL16(Xlo + o1 + k0, XLB + 4096);
#pragma unroll
    for (int is = 0; is < 4; ++is) {
      int sw = is * 256 + s;
      size_t wo = (size_t)(sw >> 2) * 256 + (sw & 3) * 8 + k0;
      GL16(Whi + wo, (char*)WsH + is * 4096 + wave * 1024);
      GL16(Wlo + wo, (char*)WsL + is * 4096 + wave * 1024);
    }
    __syncthreads();

    f16x8 ah[2], al[2];
#pragma unroll
    for (int i = 0; i < 2; ++i) {
      int ro = (wm + i*16 + col16) * 32 + quad * 8;
      ah[i] = *(const f16x8*)(XsH + ro);
      al[i] = *(const f16x8*)(XsL + ro);
    }
#pragma unroll
    for (int j = 0; j < 16; ++j) {
      int ro = (j*16 + col16) * 32 + quad * 8;
      f16x8 bh = *(const f16x8*)(WsH + ro);
      f16x8 bl = *(const f16x8*)(WsL + ro);
#pragma unroll
      for (int i = 0; i < 2; ++i) {
        acc[i][j] = __builtin_amdgcn_mfma_f32_16x16x32_f16(al[i], bh, acc[i][j], 0, 0, 0);
        acc[i][j] = __builtin_amdgcn_mfma_f32_16x16x32_f16(ah[i], bl, acc[i][j], 0, 0, 0);
        acc[i][j] = __builtin_amdgcn_mfma_f32_16x16x32_f16(ah[i], bh, acc[i][j], 0, 0, 0);
      }
    }
    __syncthreads();
  }

  // epilogue: bias + LayerNorm per row, write split f16
  // row m = bm + wm + i*16 + quad*4 + r; col = j*16 + col16
#pragma unroll
  for (int i = 0; i < 2; ++i) {
#pragma unroll
    for (int r = 0; r < 4; ++r) {
      float x[16];
      float sum = 0.f;
#pragma unroll
      for (int j = 0; j < 16; ++j) {
        float v = acc[i][j][r] + gbb[512 + j*16 + col16];
        x[j] = v;
        sum += v;
      }
#pragma unroll
      for (int msk = 1; msk < 16; msk <<= 1) sum += __shfl_xor(sum, msk, 64);
      float mu = sum * (1.f/256.f);
      float s2 = 0.f;
#pragma unroll
      for (int j = 0; j < 16; ++j) { float d = x[j] - mu; s2 += d * d; }
#pragma unroll
      for (int msk = 1; msk < 16; msk <<= 1) s2 += __shfl_xor(s2, msk, 64);
      float inv = rsqrtf(s2 * (1.f/256.f) + 1e-5f);
      size_t m = (size_t)(bm + wm + i*16 + quad*4 + r);
#pragma unroll
      for (int j = 0; j < 16; ++j) {
        int col = j*16 + col16;
        float yv = (x[j] - mu) * inv * gbb[col] + gbb[256 + col];
        f16 hh, ll; f2h_split(yv, hh, ll);
        ohi[m*256 + col] = hh;
        olo[m*256 + col] = ll;
      }
    }
  }
}

// ---------------------------------------------------------------------------
// MFMA attention v3: 512 threads, one 16-row tile per wave (waves 0..6).
// - Q prefetched to registers BEFORE the staging barrier (latency hidden).
// - Register softmax (shuffle reduce over the 16-lane col group).
// - P stored ONCE as packed u32 (f16 hi | f16 lo), stride 116 (conflict-free).
// - No barrier between P write and PV: each wave reads only the rows it wrote.
__global__ __launch_bounds__(512) void attn_mfma(const float* __restrict__ qkv,
    f16* __restrict__ aohi, f16* __restrict__ aolo) {
  const int n = blockIdx.x >> 3;
  const int h = blockIdx.x & 7;
  __shared__ f16 KH[112*32], KL[112*32];      // K rows (split)       14,336 B
  __shared__ f16 VTH[32*116], VTL[32*116];    // V^T (split), s=116   14,848 B
  __shared__ unsigned int P32[112*116];       // packed P hi|lo       51,968 B
  const int tid = threadIdx.x;
  const int wave = tid >> 6, lane = tid & 63;
  const int col16 = lane & 15, quad = lane >> 4;
  const float scale = 0.17677669529663687f;   // 1/sqrt(32)
  const float* base = qkv + (size_t)n * 100 * 768 + h * 32;
  const int tm = wave;                        // row tile owned by this wave

  // Q prefetch: issue global loads before the staging barrier
  float qv[8];
  if (tm < 7) {
    int m = tm*16 + col16; if (m > 99) m = 99;
    const float* qp = base + (size_t)m * 768 + quad*8;
    float4 q0 = *(const float4*)(qp);
    float4 q1 = *(const float4*)(qp + 4);
    qv[0]=q0.x; qv[1]=q0.y; qv[2]=q0.z; qv[3]=q0.w;
    qv[4]=q1.x; qv[5]=q1.y; qv[6]=q1.z; qv[7]=q1.w;
  } else {
#pragma unroll
    for (int j = 0; j < 8; ++j) qv[j] = 0.f;
  }

  for (int idx = tid; idx < 112*32; idx += 512) {
    int r = idx >> 5, d = idx & 31;
    float kv = 0.f, vv = 0.f;
    if (r < 100) {
      const float* p = base + (size_t)r * 768;
      kv = p[256 + d];
      vv = p[512 + d];
    }
    f16 khh, kll, vhh, vll;
    f2h_split(kv, khh, kll);
    f2h_split(vv, vhh, vll);
    KH[idx] = khh; KL[idx] = kll;
    VTH[d*116 + r] = vhh; VTL[d*116 + r] = vll;
  }
  __syncthreads();

  if (tm < 7) {
    // ---- phase 1: S row-tile in registers -> register softmax -> packed P
    f16x8 ah, al;
#pragma unroll
    for (int j = 0; j < 8; ++j) {
      f16 hh, ll; f2h_split(qv[j] * scale, hh, ll); ah[j] = hh; al[j] = ll;
    }
    f32x4 sacc[7];
#pragma unroll
    for (int tn = 0; tn < 7; ++tn) {
      int off = (tn*16 + col16)*32 + quad*8;
      f16x8 bh = *(const f16x8*)(KH + off);
      f16x8 bl = *(const f16x8*)(KL + off);
      f32x4 a = {};
      a = __builtin_amdgcn_mfma_f32_16x16x32_f16(al, bh, a, 0, 0, 0);
      a = __builtin_amdgcn_mfma_f32_16x16x32_f16(ah, bl, a, 0, 0, 0);
      a = __builtin_amdgcn_mfma_f32_16x16x32_f16(ah, bh, a, 0, 0, 0);
      sacc[tn] = a;
    }
    // lane holds S[row = tm*16 + quad*4 + r][col = tn*16 + col16];
    // mask cols >= 100 (padded K rows must not enter the softmax sum)
    if (col16 >= 4) {
      sacc[6][0] = -1e30f; sacc[6][1] = -1e30f;
      sacc[6][2] = -1e30f; sacc[6][3] = -1e30f;
    }
    float mx[4];
#pragma unroll
    for (int r = 0; r < 4; ++r) {
      float mv = sacc[0][r];
#pragma unroll
      for (int tn = 1; tn < 7; ++tn) mv = fmaxf(mv, sacc[tn][r]);
      mx[r] = mv;
    }
#pragma unroll
    for (int msk = 1; msk < 16; msk <<= 1)
#pragma unroll
      for (int r = 0; r < 4; ++r) mx[r] = fmaxf(mx[r], __shfl_xor(mx[r], msk, 64));
    float sm[4] = {0.f, 0.f, 0.f, 0.f};
#pragma unroll
    for (int tn = 0; tn < 7; ++tn)
#pragma unroll
      for (int r = 0; r < 4; ++r) {
        float p = __expf(sacc[tn][r] - mx[r]);
        sacc[tn][r] = p;
        sm[r] += p;
      }
#pragma unroll
    for (int msk = 1; msk < 16; msk <<= 1)
#pragma unroll
      for (int r = 0; r < 4; ++r) sm[r] += __shfl_xor(sm[r], msk, 64);
    float inv[4];
#pragma unroll
    for (int r = 0; r < 4; ++r) inv[r] = 1.f / sm[r];
#pragma unroll
    for (int tn = 0; tn < 7; ++tn)
#pragma unroll
      for (int r = 0; r < 4; ++r) {
        float p = sacc[tn][r] * inv[r];
        f16 hh, ll; f2h_split(p, hh, ll);
        union { struct { f16 h, l; } f; unsigned int u; } pk;
        pk.f.h = hh; pk.f.l = ll;
        P32[(tm*16 + quad*4 + r)*116 + tn*16 + col16] = pk.u;
      }

    // ---- phase 3: O = P V (same-wave P reads: no block barrier needed)
    f16x8 vh[2][4], vl[2][4];
#pragma unroll
    for (int td = 0; td < 2; ++td)
#pragma unroll
      for (int kc = 0; kc < 4; ++kc) {
        if (kc == 3 && quad >= 2) {
          f16x8 z = {};
          vh[td][kc] = z; vl[td][kc] = z;
        } else {
          int off = (td*16 + col16)*116 + kc*32 + quad*8;
          f16x4v h0 = *(const f16x4v*)(VTH + off);
          f16x4v h1 = *(const f16x4v*)(VTH + off + 4);
          f16x4v l0 = *(const f16x4v*)(VTL + off);
          f16x4v l1 = *(const f16x4v*)(VTL + off + 4);
          f16x8 hv, lv;
#pragma unroll
          for (int t = 0; t < 4; ++t) { hv[t] = h0[t]; hv[t+4] = h1[t]; lv[t] = l0[t]; lv[t+4] = l1[t]; }
          vh[td][kc] = hv; vl[td][kc] = lv;
        }
      }
    f32x4 acc[2] = {};
#pragma unroll
    for (int kc = 0; kc < 4; ++kc) {
      f16x8 ph, pl;
      if (kc == 3 && quad >= 2) {
        f16x8 z = {};
        ph = z; pl = z;
      } else {
        const unsigned int* pp = P32 + (tm*16 + col16)*116 + kc*32 + quad*8;
        f16x8 e0 = *(const f16x8*)(pp);       // h0 l0 h1 l1 h2 l2 h3 l3
        f16x8 e1 = *(const f16x8*)(pp + 4);   // h4 l4 h5 l5 h6 l6 h7 l7
        ph = __builtin_shufflevector(e0, e1, 0, 2, 4, 6, 8, 10, 12, 14);
        pl = __builtin_shufflevector(e0, e1, 1, 3, 5, 7, 9, 11, 13, 15);
      }
#pragma unroll
      for (int td = 0; td < 2; ++td) {
        acc[td] = __builtin_amdgcn_mfma_f32_16x16x32_f16(pl, vh[td][kc], acc[td], 0, 0, 0);
        acc[td] = __builtin_amdgcn_mfma_f32_16x16x32_f16(ph, vl[td][kc], acc[td], 0, 0, 0);
        acc[td] = __builtin_amdgcn_mfma_f32_16x16x32_f16(ph, vh[td][kc], acc[td], 0, 0, 0);
      }
    }
#pragma unroll
    for (int td = 0; td < 2; ++td) {
#pragma unroll
      for (int r = 0; r < 4; ++r) {
        int m = tm*16 + quad*4 + r;
        if (m < 100) {
          size_t oidx = ((size_t)n*100 + m)*256 + h*32 + td*16 + col16;
          f16 hh, ll; f2h_split(acc[td][r], hh, ll);
          aohi[oidx] = hh;
          aolo[oidx] = ll;
        }
      }
    }
  }
}

// ---------------------------------------------------------------------------
__device__ __forceinline__ float breduce(float v, float* red, int tid) {
  for (int o = 32; o > 0; o >>= 1) v += __shfl_down(v, o, 64);
  if ((tid & 63) == 0) red[tid >> 6] = v;
  __syncthreads();
  float r = red[0] + red[1] + red[2] + red[3];
  __syncthreads();
  return r;
}

// counting module: one block per n (global)
__global__ __launch_bounds__(256) void counter_kernel(
    const float* __restrict__ scores, const float* __restrict__ boxes,
    const float* __restrict__ plw, const float* __restrict__ plc,
    float* __restrict__ pred, float* __restrict__ conf_out) {
  int n = blockIdx.x, tid = threadIdx.x;
  __shared__ float plw_s[8][17], plc_s[8][17];
  __shared__ float sval[128];
  __shared__ int   sidx[128];
  __shared__ float att[36], bx[36][4];
  __shared__ float dist[36][36], scr[36][36], ds2[36][36], sim[36][36];
  __shared__ float rs[36];
  __shared__ float red[4];
  __shared__ float b_f, b_cf;
  __shared__ int   b_i;

  for (int i = tid; i < 136; i += 256) {
    (&plw_s[0][0])[i] = plw[i];
    (&plc_s[0][0])[i] = plc[i];
  }
  if (tid < 128) {
    sval[tid] = (tid < 100) ? scores[(size_t)n*100 + tid] : -1e30f;
    sidx[tid] = tid;
  }
  __syncthreads();

  for (int k = 2; k <= 128; k <<= 1) {
    for (int j = k >> 1; j > 0; j >>= 1) {
      if (tid < 128) {
        int ixj = tid ^ j;
        if (ixj > tid) {
          float va = sval[tid], vb = sval[ixj];
          int   ia = sidx[tid], ib = sidx[ixj];
          bool a_before_b = (va > vb) || (va == vb && ia < ib);
          bool ascending = ((tid & k) == 0);
          bool doswap = ascending ? !a_before_b : a_before_b;
          if (doswap) { sval[tid] = vb; sval[ixj] = va; sidx[tid] = ib; sidx[ixj] = ia; }
        }
      }
      __syncthreads();
    }
  }

  if (tid < 36) {
    att[tid] = sval[tid];
    const float* bp = boxes + ((size_t)n*100 + sidx[tid])*4;
    bx[tid][0] = bp[0]; bx[tid][1] = bp[1]; bx[tid][2] = bp[2]; bx[tid][3] = bp[3];
  }
  __syncthreads();

  for (int idx = tid; idx < 1296; idx += 256) {
    int i = idx / 36, j = idx % 36;
    float x1a = bx[i][0], y1a = bx[i][1], x2a = bx[i][2], y2a = bx[i][3];
    float x1b = bx[j][0], y1b = bx[j][1], x2b = bx[j][2], y2b = bx[j][3];
    float areaA = fmaxf(x2a - x1a, 0.f) * fmaxf(y2a - y1a, 0.f);
    float areaB = fmaxf(x2b - x1b, 0.f) * fmaxf(y2b - y1b, 0.f);
    float iw = fmaxf(fminf(x2a, x2b) - fmaxf(x1a, x1b), 0.f);
    float ih = fmaxf(fminf(y2a, y2b) - fmaxf(y1a, y1b), 0.f);
    float inter = iw * ih;
    float iou = inter / (areaA + areaB - inter + 1e-12f);
    float dd = 1.f - iou;
    float rel = att[i] * att[j];
    dist[i][j] = dd;
    scr[i][j]  = plin_f(plw_s[0], plc_s[0], rel) * plin_f(plw_s[1], plc_s[1], dd);
    ds2[i][j]  = plin_f(plw_s[3], plc_s[3], rel) * plin_f(plw_s[4], plc_s[4], dd);
  }
  __syncthreads();

  for (int idx = tid; idx < 1296; idx += 256) {
    int b = idx / 36, c = idx % 36;
    float p = plin_f(plw_s[2], plc_s[2], 1.f - fabsf(att[b] - att[c]));
    for (int a = 0; a < 36; ++a)
      p *= plin_f(plw_s[2], plc_s[2], 1.f - fabsf(ds2[a][b] - ds2[a][c]));
    sim[b][c] = p;
  }
  __syncthreads();

  if (tid < 36) {
    float s = 0.f;
    for (int c = 0; c < 36; ++c) s += sim[tid][c];
    rs[tid] = s;
  }
  __syncthreads();

  float p1 = 0.f, p4 = 0.f;
  for (int idx = tid; idx < 1296; idx += 256) {
    int b = idx / 36, c = idx % 36;
    p1 += scr[b][c] / (rs[b] * rs[c]);
    p4 += fabsf(plin_f(plw_s[6], plc_s[6], dist[b][c]) - 0.5f);
  }
  float p2 = 0.f, p3 = 0.f;
  if (tid < 36) {
    p2 = plin_f(plw_s[0], plc_s[0], att[tid]*att[tid]) / rs[tid];
    p3 = fabsf(plin_f(plw_s[5], plc_s[5], att[tid]) - 0.5f);
  }
  float s1 = breduce(p1, red, tid);
  float s2 = breduce(p2, red, tid);
  float s3 = breduce(p3, red, tid);
  float s4 = breduce(p4, red, tid);

  if (tid == 0) {
    float total = sqrtf(s1 + s2 + 1e-20f);
    float cf = plin_f(plw_s[7], plc_s[7], s3 * (1.f/36.f) + s4 * (1.f/1296.f));
    float sc = fminf(fmaxf(total, 0.f), 36.f);
    float fl = floorf(sc);
    int ii = (int)fl; if (ii > 36) ii = 36;
    b_f = sc - fl;
    b_i = ii;
    b_cf = cf;
    conf_out[n] = cf;
  }
  __syncthreads();
  if (tid < 37) {
    int ii = b_i;
    int ir = (ii + 1 > 36) ? 36 : ii + 1;
    float v = ((tid == ii) ? (1.f - b_f) : 0.f) + ((tid == ir) ? b_f : 0.f);
    pred[(size_t)n*37 + tid] = v * b_cf;
  }
}

// ---------------------------------------------------------------------------
extern "C" void kernel_launch(void* const* d_in, const int* in_sizes, int n_in,
                              void* d_out, int out_size, void* d_ws, size_t ws_size,
                              hipStream_t stream) {
  const float* v_emb = (const float*)d_in[0];
  const float* q_emb = (const float*)d_in[1];
  const float* boxes = (const float*)d_in[2];
  const float* Wq    = (const float*)d_in[3];
  const float* bq    = (const float*)d_in[4];
  const float* Wk    = (const float*)d_in[5];
  const float* bk    = (const float*)d_in[6];
  const float* Wv    = (const float*)d_in[7];
  const float* bv    = (const float*)d_in[8];
  const float* in_w  = (const float*)d_in[9];
  const float* in_b  = (const float*)d_in[10];
  const float* out_w = (const float*)d_in[11];
  const float* out_b = (const float*)d_in[12];
  const float* ln_g  = (const float*)d_in[13];
  const float* ln_b  = (const float*)d_in[14];
  const float* l0_w  = (const float*)d_in[15];
  const float* l0_b  = (const float*)d_in[16];
  const float* l1_w  = (const float*)d_in[17];
  const float* l1_b  = (const float*)d_in[18];
  const float* lo_w  = (const float*)d_in[19];
  const float* lo_b  = (const float*)d_in[20];
  const float* pw    = (const float*)d_in[21];

  float* ws = (float*)d_ws;
  // persistent fp32 region
  float* plw   = ws + 0;        // 136 (reserve 256)
  float* plc   = ws + 256;      // 136 (reserve 256)
  float* cbuf  = ws + 512;      // 768
  float* x1    = ws + 1280;     // 614400 -> 615680
  // persistent f16 region (element offsets within hb)
  f16* hb = (f16*)(ws + 615680);
  f16* A_hi    = hb + 0;         // 768*256 = 196608
  f16* A_lo    = hb + 196608;
  f16* outw_hi = hb + 393216;    // 256*256 = 65536
  f16* outw_lo = hb + 458752;
  f16* l0w_hi  = hb + 524288;    // 640*256 = 163840
  f16* l0w_lo  = hb + 688128;
  f16* l1w_hi  = hb + 851968;    // 640*256 = 163840
  f16* l1w_lo  = hb + 1015808;
  f16* qp_hi   = hb + 1179648;   // 1024*256 = 262144
  f16* qp_lo   = hb + 1441792;
  f16* v_hi    = hb + 1703936;   // 102400*256 = 26214400
  f16* v_lo    = hb + 27918336;  // end 54132736 f16 = 27066368 float slots
  const size_t small_floats = 615680 + 27066368;   // 27,682,048 floats (~111 MB)

  // per-image chunk cost (floats):
  //   qkv 76800 + mlb partials 2000 (100 rows x 10 float2) + 4x12800 f16 halves
  //   = 130000
  size_t avail = (ws_size / 4 > small_floats) ? (ws_size / 4 - small_floats) : 0;
  int NC = 1024;
  while (NC > 32 && (size_t)NC * 130000ull > avail) NC >>= 1;

  float* qkv_c = ws + small_floats;                   // NC*76800
  float2* part = (float2*)(qkv_c + (size_t)NC * 76800); // NC*1000 float2 = NC*2000 floats
  f16* ao_hi  = (f16*)((float*)(void*)part + (size_t)NC * 2000);
  f16* ao_lo  = ao_hi + (size_t)NC * 25600;
  f16* int_hi = ao_lo + (size_t)NC * 25600;
  f16* int_lo = int_hi + (size_t)NC * 25600;

  float* out    = (float*)d_out;
  float* scores = out;             // N*R
  float* pred   = out + 102400;    // N*37
  float* conf   = out + 140288;    // N

  prep_plin<<<1, 64, 0, stream>>>(pw, plw, plc);
  fuse_c<<<3, 256, 0, stream>>>(in_w, in_b, bq, bk, bv, cbuf);
  fuse_A<<<768, 256, 0, stream>>>(in_w, Wq, Wk, Wv, A_hi, A_lo);
  split_vec<<<(65536/4 + 255)/256, 256, 0, stream>>>(out_w, outw_hi, outw_lo, 65536/4);
  conv_w600<<<640, 256, 0, stream>>>(l0_w, l0w_hi, l0w_lo);
  conv_w600<<<640, 256, 0, stream>>>(l1_w, l1w_hi, l1w_lo);
  split_vec<<<(26214400/4 + 255)/256, 256, 0, stream>>>(v_emb, v_hi, v_lo, 26214400/4);
  pool_split<<<N_, 256, 0, stream>>>(q_emb, qp_hi, qp_lo);
  {
    dim3 gx(1024/128, 5);   // x1 = q_pool @ l1_w^T + l1_b  (M=1024, Opad=640)
    gemm_f16s<true><<<gx, 256, 0, stream>>>(qp_hi, qp_lo, l1w_hi, l1w_lo,
                                            l1_b, x1, 600);
  }

  for (int n0 = 0; n0 < N_; n0 += NC) {
    const int M = NC * 100;
    const size_t voff = (size_t)n0 * 100 * 256;

    dim3 g1(M / 128, 6);   // O=768
    gemm_f16s<false><<<g1, 256, 0, stream>>>(v_hi + voff, v_lo + voff,
                                             A_hi, A_lo, cbuf, qkv_c, 768);

    attn_mfma<<<NC * H_, 512, 0, stream>>>(qkv_c, ao_hi, ao_lo);

    // out-proj + fused LayerNorm -> split f16
    gemm2_ln<<<M / 128, 256, 0, stream>>>(ao_hi, ao_lo, outw_hi, outw_lo,
                                          out_b, ln_g, ln_b, int_hi, int_lo);

    // l0 GEMM + fused MLB partial reduction (x0 never materialized)
    dim3 g3(M / 128, 5);   // Opad=640
    gemm_l0_mlb<<<g3, 256, 0, stream>>>(int_hi, int_lo, l0w_hi, l0w_lo,
                                        l0_b, x1 + (size_t)n0 * 600, lo_w, part);

    mlb_reduce<<<(M + 255)/256, 256, 0, stream>>>(part, lo_b,
                                                  scores + (size_t)n0 * 100, M);
  }

  counter_kernel<<<N_, 256, 0, stream>>>(scores, boxes, plw, plc, pred, conf);
}

// Round 5
// 881.966 us; speedup vs baseline: 1.1401x; 1.1401x over previous
//
#include <hip/hip_runtime.h>

// Problem constants
#define N_   1024
#define R_   100
#define D_   256
#define T_   14
#define H_   8
#define DH_  32
#define MM_  600
#define OBJ_ 36

typedef _Float16 f16;
typedef __attribute__((ext_vector_type(8))) _Float16 f16x8;
typedef __attribute__((ext_vector_type(4))) _Float16 f16x4v;
typedef __attribute__((ext_vector_type(4))) float f32x4;

// fp32 -> (hi, lo) fp16 split: x ≈ hi + lo with ~22-bit combined mantissa
__device__ __forceinline__ void f2h_split(float x, f16& hi, f16& lo) {
  hi = (_Float16)x;
  lo = (_Float16)(x - (float)hi);
}

// async 16B global->LDS
#define GL16(gp, lp) __builtin_amdgcn_global_load_lds( \
    (const __attribute__((address_space(1))) void*)(gp), \
    (__attribute__((address_space(3))) void*)(lp), 16, 0, 0)

// XCD-aware remap: co-locate all gridDim.y variants of one x-panel on one XCD
// (consecutive slots) so the shared X-panel is fetched into that XCD's L2 once.
// Bijective when gridDim.x % 8 == 0; identity otherwise. Perf-only.
__device__ __forceinline__ void xcd_remap(int& bx, int& by) {
  int nx = gridDim.x, ny = gridDim.y;
  if ((nx & 7) == 0) {
    int id = bx + nx * by;
    int xcd = id & 7, slot = id >> 3;
    bx = xcd + 8 * (slot / ny);
    by = slot % ny;
  }
}

// ---------------------------------------------------------------------------
__device__ __forceinline__ float plin_f(const float* __restrict__ w,
                                        const float* __restrict__ cs, float x) {
  float xc = fminf(fmaxf(x, 0.f), 1.f);
  float y  = 16.f * xc;
  float fy = floorf(y);
  int   i  = (int)fy;              // 0..16
  float f  = y - fy;
  int   ip = i + 1; if (ip > 16) ip = 16;
  return cs[i] + f * w[ip];
}

// ---------------------------------------------------------------------------
__global__ void prep_plin(const float* __restrict__ pw, float* __restrict__ plw,
                          float* __restrict__ plc) {
  int p = threadIdx.x;
  if (p < 8) {
    float w[17];
    float sum = 0.f;
    w[0] = 0.f;
    for (int k = 1; k < 17; ++k) { w[k] = fabsf(pw[p*17 + k]); sum += w[k]; }
    float inv = 1.f / sum;
    float c = 0.f;
    for (int k = 0; k < 17; ++k) {
      float wk = w[k] * inv;
      c += wk;
      plw[p*17 + k] = wk;
      plc[p*17 + k] = c;
    }
  }
}

// ---------------------------------------------------------------------------
__global__ void fuse_c(const float* __restrict__ in_w, const float* __restrict__ in_b,
                       const float* __restrict__ bq, const float* __restrict__ bk,
                       const float* __restrict__ bv, float* __restrict__ c) {
  int i = blockIdx.x * blockDim.x + threadIdx.x;
  if (i < 768) {
    const float* bsel = (i < 256) ? bq : ((i < 512) ? bk : bv);
    float acc = in_b[i];
    for (int o = 0; o < 256; ++o) acc += in_w[(size_t)i*256 + o] * bsel[o];
    c[i] = acc;
  }
}

__global__ __launch_bounds__(256) void fuse_A(const float* __restrict__ in_w,
    const float* __restrict__ Wq, const float* __restrict__ Wk,
    const float* __restrict__ Wv, f16* __restrict__ Ahi, f16* __restrict__ Alo) {
  int i = blockIdx.x;        // 0..767
  int j = threadIdx.x;       // 0..255
  const float* Wsel = (i < 256) ? Wq : ((i < 512) ? Wk : Wv);
  __shared__ float row[256];
  row[j] = in_w[(size_t)i*256 + j];
  __syncthreads();
  float acc = 0.f;
  for (int o = 0; o < 256; ++o) acc += row[o] * Wsel[(size_t)o*256 + j];
  f16 h, l; f2h_split(acc, h, l);
  Ahi[(size_t)i*256 + j] = h;
  Alo[(size_t)i*256 + j] = l;
}

__global__ __launch_bounds__(256) void split_vec(const float* __restrict__ in,
    f16* __restrict__ hi, f16* __restrict__ lo, int n4) {
  int i = blockIdx.x * blockDim.x + threadIdx.x;
  if (i < n4) {
    float4 v = ((const float4*)in)[i];
    union { f16 h[4]; ushort4 u; } H, L;
    f2h_split(v.x, H.h[0], L.h[0]);
    f2h_split(v.y, H.h[1], L.h[1]);
    f2h_split(v.z, H.h[2], L.h[2]);
    f2h_split(v.w, H.h[3], L.h[3]);
    ((ushort4*)hi)[i] = H.u;
    ((ushort4*)lo)[i] = L.u;
  }
}

// 600x256 weight -> split fp16 padded to 640x256 (zero rows beyond 600)
__global__ __launch_bounds__(256) void conv_w600(const float* __restrict__ w,
    f16* __restrict__ hi, f16* __restrict__ lo) {
  int o = blockIdx.x;        // 0..639
  int j = threadIdx.x;       // 0..255
  f16 h = (f16)0.f, l = (f16)0.f;
  if (o < 600) f2h_split(w[(size_t)o*256 + j], h, l);
  hi[(size_t)o*256 + j] = h;
  lo[(size_t)o*256 + j] = l;
}

// q_emb mean-pool -> split fp16 (one block per n)
__global__ __launch_bounds__(256) void pool_split(const float* __restrict__ q_emb,
    f16* __restrict__ qph, f16* __restrict__ qpl) {
  int n = blockIdx.x, tid = threadIdx.x;
  float s = 0.f;
  for (int t = 0; t < 14; ++t) s += q_emb[((size_t)n*14 + t)*256 + tid];
  s *= (1.f/14.f);
  f16 h, l; f2h_split(s, h, l);
  qph[(size_t)n*256 + tid] = h;
  qpl[(size_t)n*256 + tid] = l;
}

// ---------------------------------------------------------------------------
// split-fp16 MFMA GEMM (fp32-accurate): C[m][o] = sum_k X[m][k]*W[o][k] + bias[o]
template<bool BOUND>
__global__ __launch_bounds__(256) void gemm_f16s(
    const f16* __restrict__ Xhi, const f16* __restrict__ Xlo,
    const f16* __restrict__ Whi, const f16* __restrict__ Wlo,
    const float* __restrict__ bias, float* __restrict__ C, int Oreal) {
  __shared__ f16 XsH[128 * 32];
  __shared__ f16 XsL[128 * 32];
  __shared__ f16 WsH[128 * 32];
  __shared__ f16 WsL[128 * 32];
  const int tid  = threadIdx.x;
  const int wave = tid >> 6, lane = tid & 63;
  int bx = blockIdx.x, by = blockIdx.y;
  xcd_remap(bx, by);
  const int bm = bx * 128, bn = by * 128;
  const int wm = (wave & 1) * 64, wn = (wave >> 1) * 64;
  const int col = lane & 15, quad = lane >> 4;

  const int s = wave * 64 + lane;
  const int r0 = s >> 2,         cseg = (s & 3) * 8;
  const int r1 = (s + 256) >> 2;
  const size_t o0 = (size_t)(bm + r0) * 256 + cseg;
  const size_t o1 = (size_t)(bm + r1) * 256 + cseg;
  const size_t p0 = (size_t)(bn + r0) * 256 + cseg;
  const size_t p1 = (size_t)(bn + r1) * 256 + cseg;
  char* XHB = (char*)XsH + wave * 1024;
  char* XLB = (char*)XsL + wave * 1024;
  char* WHB = (char*)WsH + wave * 1024;
  char* WLB = (char*)WsL + wave * 1024;

  f32x4 acc[4][4] = {};

  for (int k0 = 0; k0 < 256; k0 += 32) {
    GL16(Xhi + o0 + k0, XHB);
    GL16(Xhi + o1 + k0, XHB + 4096);
    GL16(Xlo + o0 + k0, XLB);
    GL16(Xlo + o1 + k0, XLB + 4096);
    GL16(Whi + p0 + k0, WHB);
    GL16(Whi + p1 + k0, WHB + 4096);
    GL16(Wlo + p0 + k0, WLB);
    GL16(Wlo + p1 + k0, WLB + 4096);
    __syncthreads();

    f16x8 ah[4], al[4], bh[4], bl[4];
#pragma unroll
    for (int i = 0; i < 4; ++i) {
      int ro = (wm + i*16 + col) * 32 + quad * 8;
      ah[i] = *(const f16x8*)(XsH + ro);
      al[i] = *(const f16x8*)(XsL + ro);
    }
#pragma unroll
    for (int j = 0; j < 4; ++j) {
      int ro = (wn + j*16 + col) * 32 + quad * 8;
      bh[j] = *(const f16x8*)(WsH + ro);
      bl[j] = *(const f16x8*)(WsL + ro);
    }
#pragma unroll
    for (int i = 0; i < 4; ++i)
#pragma unroll
      for (int j = 0; j < 4; ++j) {
        acc[i][j] = __builtin_amdgcn_mfma_f32_16x16x32_f16(al[i], bh[j], acc[i][j], 0, 0, 0);
        acc[i][j] = __builtin_amdgcn_mfma_f32_16x16x32_f16(ah[i], bl[j], acc[i][j], 0, 0, 0);
        acc[i][j] = __builtin_amdgcn_mfma_f32_16x16x32_f16(ah[i], bh[j], acc[i][j], 0, 0, 0);
      }
    __syncthreads();
  }

#pragma unroll
  for (int j = 0; j < 4; ++j) {
    int o = bn + wn + j*16 + col;
    if (BOUND && o >= Oreal) continue;
    float bo = bias[o];
#pragma unroll
    for (int i = 0; i < 4; ++i) {
#pragma unroll
      for (int r = 0; r < 4; ++r) {
        int m = bm + wm + i*16 + quad*4 + r;
        C[(size_t)m * Oreal + o] = acc[i][j][r] + bo;
      }
    }
  }
}

// ---------------------------------------------------------------------------
// l0 GEMM with FUSED MLB partial reduction v3.
// - LDS kept at 32 KB (5 blocks/CU; v2's extra LDS cost 2 blocks -> regression).
// - Per-lane x1/bias/lo_w preloaded to 16 registers before the epilogue: a
//   wave's 64-row tile spans at most 2 images, so 2 register sets + one
//   compare replace 64 scattered global loads + 16 integer divisions.
// - ss uses rt^2 == |v| identity (saves the square).
__global__ __launch_bounds__(256) void gemm_l0_mlb(
    const f16* __restrict__ Xhi, const f16* __restrict__ Xlo,
    const f16* __restrict__ Whi, const f16* __restrict__ Wlo,
    const float* __restrict__ bias, const float* __restrict__ x1,
    const float* __restrict__ lo_w, float2* __restrict__ part) {
  __shared__ f16 XsH[128 * 32];
  __shared__ f16 XsL[128 * 32];
  __shared__ f16 WsH[128 * 32];
  __shared__ f16 WsL[128 * 32];
  const int tid  = threadIdx.x;
  const int wave = tid >> 6, lane = tid & 63;
  int bx = blockIdx.x, by = blockIdx.y;
  xcd_remap(bx, by);
  const int bm = bx * 128, bn = by * 128;
  const int wm = (wave & 1) * 64, wn = (wave >> 1) * 64;
  const int col = lane & 15, quad = lane >> 4;

  const int s = wave * 64 + lane;
  const int r0 = s >> 2,         cseg = (s & 3) * 8;
  const int r1 = (s + 256) >> 2;
  const size_t o0 = (size_t)(bm + r0) * 256 + cseg;
  const size_t o1 = (size_t)(bm + r1) * 256 + cseg;
  const size_t p0 = (size_t)(bn + r0) * 256 + cseg;
  const size_t p1 = (size_t)(bn + r1) * 256 + cseg;
  char* XHB = (char*)XsH + wave * 1024;
  char* XLB = (char*)XsL + wave * 1024;
  char* WHB = (char*)WsH + wave * 1024;
  char* WLB = (char*)WsL + wave * 1024;

  f32x4 acc[4][4] = {};

  for (int k0 = 0; k0 < 256; k0 += 32) {
    GL16(Xhi + o0 + k0, XHB);
    GL16(Xhi + o1 + k0, XHB + 4096);
    GL16(Xlo + o0 + k0, XLB);
    GL16(Xlo + o1 + k0, XLB + 4096);
    GL16(Whi + p0 + k0, WHB);
    GL16(Whi + p1 + k0, WHB + 4096);
    GL16(Wlo + p0 + k0, WLB);
    GL16(Wlo + p1 + k0, WLB + 4096);
    __syncthreads();

    f16x8 ah[4], al[4], bh[4], bl[4];
#pragma unroll
    for (int i = 0; i < 4; ++i) {
      int ro = (wm + i*16 + col) * 32 + quad * 8;
      ah[i] = *(const f16x8*)(XsH + ro);
      al[i] = *(const f16x8*)(XsL + ro);
    }
#pragma unroll
    for (int j = 0; j < 4; ++j) {
      int ro = (wn + j*16 + col) * 32 + quad * 8;
      bh[j] = *(const f16x8*)(WsH + ro);
      bl[j] = *(const f16x8*)(WsL + ro);
    }
#pragma unroll
    for (int i = 0; i < 4; ++i)
#pragma unroll
      for (int j = 0; j < 4; ++j) {
        acc[i][j] = __builtin_amdgcn_mfma_f32_16x16x32_f16(al[i], bh[j], acc[i][j], 0, 0, 0);
        acc[i][j] = __builtin_amdgcn_mfma_f32_16x16x32_f16(ah[i], bl[j], acc[i][j], 0, 0, 0);
        acc[i][j] = __builtin_amdgcn_mfma_f32_16x16x32_f16(ah[i], bh[j], acc[i][j], 0, 0, 0);
      }
    __syncthreads();
  }

  // ---- fused MLB epilogue v3 ----
  const int M = (int)gridDim.x * 128;        // chunk rows (== NC*100)
  const int NCimg = M / 100;
  const int mA = bm + wm;                    // first row of this wave's tile
  const int imgA = mA / 100;
  int imgB = imgA + 1; if (imgB > NCimg - 1) imgB = NCimg - 1;
  const int rB = (imgA + 1) * 100;           // first row belonging to imgB

  float bo4[4], lw4[4], x1A[4], x1B[4];
#pragma unroll
  for (int j = 0; j < 4; ++j) {
    int o = bn + wn + j*16 + col;
    bool v = (o < 600);
    bo4[j] = v ? bias[o] : 0.f;
    lw4[j] = v ? lo_w[o] : 0.f;
    x1A[j] = v ? x1[(size_t)imgA*600 + o] : 0.f;
    x1B[j] = v ? x1[(size_t)imgB*600 + o] : 0.f;
  }

#pragma unroll
  for (int i = 0; i < 4; ++i) {
#pragma unroll
    for (int rr = 0; rr < 4; ++rr) {
      int m = bm + wm + i*16 + quad*4 + rr;
      bool hiImg = (m >= rB);
      float ss = 0.f, dt = 0.f;
#pragma unroll
      for (int j = 0; j < 4; ++j) {
        float xv = hiImg ? x1B[j] : x1A[j];
        float v = (acc[i][j][rr] + bo4[j]) * xv;
        float av = fabsf(v);
        ss += av;                             // rt*rt == |v|
        dt += copysignf(sqrtf(av), v) * lw4[j];
      }
#pragma unroll
      for (int msk = 1; msk < 16; msk <<= 1) {
        ss += __shfl_xor(ss, msk, 64);
        dt += __shfl_xor(dt, msk, 64);
      }
      if (col == 0) {
        float2 pv; pv.x = ss; pv.y = dt;
        part[(size_t)m * 10 + by * 2 + (wn >> 6)] = pv;
      }
    }
  }
}

// combine 10 partials per row -> normalize -> sigmoid -> scores
__global__ __launch_bounds__(256) void mlb_reduce(const float2* __restrict__ part,
    const float* __restrict__ lo_b, float* __restrict__ out, int M) {
  int m = blockIdx.x * 256 + threadIdx.x;
  if (m < M) {
    const float2* p = part + (size_t)m * 10;
    float ss = 0.f, dt = 0.f;
#pragma unroll
    for (int t = 0; t < 10; ++t) { float2 v = p[t]; ss += v.x; dt += v.y; }
    float sc = dt / fmaxf(sqrtf(ss), 1e-12f) + lo_b[0];
    out[m] = 1.f / (1.f + __expf(-sc));
  }
}

// ---------------------------------------------------------------------------
// out-proj GEMM + fused LayerNorm: tile 128 rows x FULL 256 cols per block.
// inter = LN(ao @ out_w^T + out_b); writes split f16 directly.
__global__ __launch_bounds__(256) void gemm2_ln(
    const f16* __restrict__ Xhi, const f16* __restrict__ Xlo,
    const f16* __restrict__ Whi, const f16* __restrict__ Wlo,
    const float* __restrict__ bias, const float* __restrict__ g,
    const float* __restrict__ b, f16* __restrict__ ohi, f16* __restrict__ olo) {
  __shared__ f16 XsH[128 * 32];
  __shared__ f16 XsL[128 * 32];
  __shared__ f16 WsH[256 * 32];
  __shared__ f16 WsL[256 * 32];
  __shared__ float gbb[768];   // g | b | bias
  const int tid  = threadIdx.x;
  const int wave = tid >> 6, lane = tid & 63;
  const int bm = blockIdx.x * 128;
  const int wm = wave * 32;
  const int col16 = lane & 15, quad = lane >> 4;

  for (int i = tid; i < 768; i += 256)
    gbb[i] = (i < 256) ? g[i] : ((i < 512) ? b[i - 256] : bias[i - 512]);

  const int s = wave * 64 + lane;
  const int rx0 = s >> 2, cseg = (s & 3) * 8;
  const int rx1 = (s + 256) >> 2;
  const size_t o0 = (size_t)(bm + rx0) * 256 + cseg;
  const size_t o1 = (size_t)(bm + rx1) * 256 + cseg;
  char* XHB = (char*)XsH + wave * 1024;
  char* XLB = (char*)XsL + wave * 1024;

  f32x4 acc[2][16] = {};

  for (int k0 = 0; k0 < 256; k0 += 32) {
    GL16(Xhi + o0 + k0, XHB);
    GL16(Xhi + o1 + k0, XHB + 4096);
    GL16(Xlo + o0 + k0, XLB);
    GL16(Xlo + o1 + k0, XLB + 4096);
#pragma unroll
    for (int is = 0; is < 4; ++is) {
      int sw = is * 256 + s;
      size_t wo = (size_t)(sw >> 2) * 256 + (sw & 3) * 8 + k0;
      GL16(Whi + wo, (char*)WsH + is * 4096 + wave * 1024);
      GL16(Wlo + wo, (char*)WsL + is * 4096 + wave * 1024);
    }
    __syncthreads();

    f16x8 ah[2], al[2];
#pragma unroll
    for (int i = 0; i < 2; ++i) {
      int ro = (wm + i*16 + col16) * 32 + quad * 8;
      ah[i] = *(const f16x8*)(XsH + ro);
      al[i] = *(const f16x8*)(XsL + ro);
    }
#pragma unroll
    for (int j = 0; j < 16; ++j) {
      int ro = (j*16 + col16) * 32 + quad * 8;
      f16x8 bh = *(const f16x8*)(WsH + ro);
      f16x8 bl = *(const f16x8*)(WsL + ro);
#pragma unroll
      for (int i = 0; i < 2; ++i) {
        acc[i][j] = __builtin_amdgcn_mfma_f32_16x16x32_f16(al[i], bh, acc[i][j], 0, 0, 0);
        acc[i][j] = __builtin_amdgcn_mfma_f32_16x16x32_f16(ah[i], bl, acc[i][j], 0, 0, 0);
        acc[i][j] = __builtin_amdgcn_mfma_f32_16x16x32_f16(ah[i], bh, acc[i][j], 0, 0, 0);
      }
    }
    __syncthreads();
  }

  // epilogue: bias + LayerNorm per row, write split f16
  // row m = bm + wm + i*16 + quad*4 + r; col = j*16 + col16
#pragma unroll
  for (int i = 0; i < 2; ++i) {
#pragma unroll
    for (int r = 0; r < 4; ++r) {
      float x[16];
      float sum = 0.f;
#pragma unroll
      for (int j = 0; j < 16; ++j) {
        float v = acc[i][j][r] + gbb[512 + j*16 + col16];
        x[j] = v;
        sum += v;
      }
#pragma unroll
      for (int msk = 1; msk < 16; msk <<= 1) sum += __shfl_xor(sum, msk, 64);
      float mu = sum * (1.f/256.f);
      float s2 = 0.f;
#pragma unroll
      for (int j = 0; j < 16; ++j) { float d = x[j] - mu; s2 += d * d; }
#pragma unroll
      for (int msk = 1; msk < 16; msk <<= 1) s2 += __shfl_xor(s2, msk, 64);
      float inv = rsqrtf(s2 * (1.f/256.f) + 1e-5f);
      size_t m = (size_t)(bm + wm + i*16 + quad*4 + r);
#pragma unroll
      for (int j = 0; j < 16; ++j) {
        int col = j*16 + col16;
        float yv = (x[j] - mu) * inv * gbb[col] + gbb[256 + col];
        f16 hh, ll; f2h_split(yv, hh, ll);
        ohi[m*256 + col] = hh;
        olo[m*256 + col] = ll;
      }
    }
  }
}

// ---------------------------------------------------------------------------
// MFMA attention v3: 512 threads, one 16-row tile per wave (waves 0..6).
// - Q prefetched to registers BEFORE the staging barrier (latency hidden).
// - Register softmax (shuffle reduce over the 16-lane col group).
// - P stored ONCE as packed u32 (f16 hi | f16 lo), stride 116 (conflict-free).
// - No barrier between P write and PV: each wave reads only the rows it wrote.
__global__ __launch_bounds__(512) void attn_mfma(const float* __restrict__ qkv,
    f16* __restrict__ aohi, f16* __restrict__ aolo) {
  const int n = blockIdx.x >> 3;
  const int h = blockIdx.x & 7;
  __shared__ f16 KH[112*32], KL[112*32];      // K rows (split)       14,336 B
  __shared__ f16 VTH[32*116], VTL[32*116];    // V^T (split), s=116   14,848 B
  __shared__ unsigned int P32[112*116];       // packed P hi|lo       51,968 B
  const int tid = threadIdx.x;
  const int wave = tid >> 6, lane = tid & 63;
  const int col16 = lane & 15, quad = lane >> 4;
  const float scale = 0.17677669529663687f;   // 1/sqrt(32)
  const float* base = qkv + (size_t)n * 100 * 768 + h * 32;
  const int tm = wave;                        // row tile owned by this wave

  // Q prefetch: issue global loads before the staging barrier
  float qv[8];
  if (tm < 7) {
    int m = tm*16 + col16; if (m > 99) m = 99;
    const float* qp = base + (size_t)m * 768 + quad*8;
    float4 q0 = *(const float4*)(qp);
    float4 q1 = *(const float4*)(qp + 4);
    qv[0]=q0.x; qv[1]=q0.y; qv[2]=q0.z; qv[3]=q0.w;
    qv[4]=q1.x; qv[5]=q1.y; qv[6]=q1.z; qv[7]=q1.w;
  } else {
#pragma unroll
    for (int j = 0; j < 8; ++j) qv[j] = 0.f;
  }

  for (int idx = tid; idx < 112*32; idx += 512) {
    int r = idx >> 5, d = idx & 31;
    float kv = 0.f, vv = 0.f;
    if (r < 100) {
      const float* p = base + (size_t)r * 768;
      kv = p[256 + d];
      vv = p[512 + d];
    }
    f16 khh, kll, vhh, vll;
    f2h_split(kv, khh, kll);
    f2h_split(vv, vhh, vll);
    KH[idx] = khh; KL[idx] = kll;
    VTH[d*116 + r] = vhh; VTL[d*116 + r] = vll;
  }
  __syncthreads();

  if (tm < 7) {
    // ---- phase 1: S row-tile in registers -> register softmax -> packed P
    f16x8 ah, al;
#pragma unroll
    for (int j = 0; j < 8; ++j) {
      f16 hh, ll; f2h_split(qv[j] * scale, hh, ll); ah[j] = hh; al[j] = ll;
    }
    f32x4 sacc[7];
#pragma unroll
    for (int tn = 0; tn < 7; ++tn) {
      int off = (tn*16 + col16)*32 + quad*8;
      f16x8 bh = *(const f16x8*)(KH + off);
      f16x8 bl = *(const f16x8*)(KL + off);
      f32x4 a = {};
      a = __builtin_amdgcn_mfma_f32_16x16x32_f16(al, bh, a, 0, 0, 0);
      a = __builtin_amdgcn_mfma_f32_16x16x32_f16(ah, bl, a, 0, 0, 0);
      a = __builtin_amdgcn_mfma_f32_16x16x32_f16(ah, bh, a, 0, 0, 0);
      sacc[tn] = a;
    }
    // lane holds S[row = tm*16 + quad*4 + r][col = tn*16 + col16];
    // mask cols >= 100 (padded K rows must not enter the softmax sum)
    if (col16 >= 4) {
      sacc[6][0] = -1e30f; sacc[6][1] = -1e30f;
      sacc[6][2] = -1e30f; sacc[6][3] = -1e30f;
    }
    float mx[4];
#pragma unroll
    for (int r = 0; r < 4; ++r) {
      float mv = sacc[0][r];
#pragma unroll
      for (int tn = 1; tn < 7; ++tn) mv = fmaxf(mv, sacc[tn][r]);
      mx[r] = mv;
    }
#pragma unroll
    for (int msk = 1; msk < 16; msk <<= 1)
#pragma unroll
      for (int r = 0; r < 4; ++r) mx[r] = fmaxf(mx[r], __shfl_xor(mx[r], msk, 64));
    float sm[4] = {0.f, 0.f, 0.f, 0.f};
#pragma unroll
    for (int tn = 0; tn < 7; ++tn)
#pragma unroll
      for (int r = 0; r < 4; ++r) {
        float p = __expf(sacc[tn][r] - mx[r]);
        sacc[tn][r] = p;
        sm[r] += p;
      }
#pragma unroll
    for (int msk = 1; msk < 16; msk <<= 1)
#pragma unroll
      for (int r = 0; r < 4; ++r) sm[r] += __shfl_xor(sm[r], msk, 64);
    float inv[4];
#pragma unroll
    for (int r = 0; r < 4; ++r) inv[r] = 1.f / sm[r];
#pragma unroll
    for (int tn = 0; tn < 7; ++tn)
#pragma unroll
      for (int r = 0; r < 4; ++r) {
        float p = sacc[tn][r] * inv[r];
        f16 hh, ll; f2h_split(p, hh, ll);
        union { struct { f16 h, l; } f; unsigned int u; } pk;
        pk.f.h = hh; pk.f.l = ll;
        P32[(tm*16 + quad*4 + r)*116 + tn*16 + col16] = pk.u;
      }

    // ---- phase 3: O = P V (same-wave P reads: no block barrier needed)
    f16x8 vh[2][4], vl[2][4];
#pragma unroll
    for (int td = 0; td < 2; ++td)
#pragma unroll
      for (int kc = 0; kc < 4; ++kc) {
        if (kc == 3 && quad >= 2) {
          f16x8 z = {};
          vh[td][kc] = z; vl[td][kc] = z;
        } else {
          int off = (td*16 + col16)*116 + kc*32 + quad*8;
          f16x4v h0 = *(const f16x4v*)(VTH + off);
          f16x4v h1 = *(const f16x4v*)(VTH + off + 4);
          f16x4v l0 = *(const f16x4v*)(VTL + off);
          f16x4v l1 = *(const f16x4v*)(VTL + off + 4);
          f16x8 hv, lv;
#pragma unroll
          for (int t = 0; t < 4; ++t) { hv[t] = h0[t]; hv[t+4] = h1[t]; lv[t] = l0[t]; lv[t+4] = l1[t]; }
          vh[td][kc] = hv; vl[td][kc] = lv;
        }
      }
    f32x4 acc[2] = {};
#pragma unroll
    for (int kc = 0; kc < 4; ++kc) {
      f16x8 ph, pl;
      if (kc == 3 && quad >= 2) {
        f16x8 z = {};
        ph = z; pl = z;
      } else {
        const unsigned int* pp = P32 + (tm*16 + col16)*116 + kc*32 + quad*8;
        f16x8 e0 = *(const f16x8*)(pp);       // h0 l0 h1 l1 h2 l2 h3 l3
        f16x8 e1 = *(const f16x8*)(pp + 4);   // h4 l4 h5 l5 h6 l6 h7 l7
        ph = __builtin_shufflevector(e0, e1, 0, 2, 4, 6, 8, 10, 12, 14);
        pl = __builtin_shufflevector(e0, e1, 1, 3, 5, 7, 9, 11, 13, 15);
      }
#pragma unroll
      for (int td = 0; td < 2; ++td) {
        acc[td] = __builtin_amdgcn_mfma_f32_16x16x32_f16(pl, vh[td][kc], acc[td], 0, 0, 0);
        acc[td] = __builtin_amdgcn_mfma_f32_16x16x32_f16(ph, vl[td][kc], acc[td], 0, 0, 0);
        acc[td] = __builtin_amdgcn_mfma_f32_16x16x32_f16(ph, vh[td][kc], acc[td], 0, 0, 0);
      }
    }
#pragma unroll
    for (int td = 0; td < 2; ++td) {
#pragma unroll
      for (int r = 0; r < 4; ++r) {
        int m = tm*16 + quad*4 + r;
        if (m < 100) {
          size_t oidx = ((size_t)n*100 + m)*256 + h*32 + td*16 + col16;
          f16 hh, ll; f2h_split(acc[td][r], hh, ll);
          aohi[oidx] = hh;
          aolo[oidx] = ll;
        }
      }
    }
  }
}

// ---------------------------------------------------------------------------
__device__ __forceinline__ float breduce(float v, float* red, int tid) {
  for (int o = 32; o > 0; o >>= 1) v += __shfl_down(v, o, 64);
  if ((tid & 63) == 0) red[tid >> 6] = v;
  __syncthreads();
  float r = red[0] + red[1] + red[2] + red[3];
  __syncthreads();
  return r;
}

// counting module: one block per n (global)
__global__ __launch_bounds__(256) void counter_kernel(
    const float* __restrict__ scores, const float* __restrict__ boxes,
    const float* __restrict__ plw, const float* __restrict__ plc,
    float* __restrict__ pred, float* __restrict__ conf_out) {
  int n = blockIdx.x, tid = threadIdx.x;
  __shared__ float plw_s[8][17], plc_s[8][17];
  __shared__ float sval[128];
  __shared__ int   sidx[128];
  __shared__ float att[36], bx[36][4];
  __shared__ float dist[36][36], scr[36][36], ds2[36][36], sim[36][36];
  __shared__ float rs[36];
  __shared__ float red[4];
  __shared__ float b_f, b_cf;
  __shared__ int   b_i;

  for (int i = tid; i < 136; i += 256) {
    (&plw_s[0][0])[i] = plw[i];
    (&plc_s[0][0])[i] = plc[i];
  }
  if (tid < 128) {
    sval[tid] = (tid < 100) ? scores[(size_t)n*100 + tid] : -1e30f;
    sidx[tid] = tid;
  }
  __syncthreads();

  for (int k = 2; k <= 128; k <<= 1) {
    for (int j = k >> 1; j > 0; j >>= 1) {
      if (tid < 128) {
        int ixj = tid ^ j;
        if (ixj > tid) {
          float va = sval[tid], vb = sval[ixj];
          int   ia = sidx[tid], ib = sidx[ixj];
          bool a_before_b = (va > vb) || (va == vb && ia < ib);
          bool ascending = ((tid & k) == 0);
          bool doswap = ascending ? !a_before_b : a_before_b;
          if (doswap) { sval[tid] = vb; sval[ixj] = va; sidx[tid] = ib; sidx[ixj] = ia; }
        }
      }
      __syncthreads();
    }
  }

  if (tid < 36) {
    att[tid] = sval[tid];
    const float* bp = boxes + ((size_t)n*100 + sidx[tid])*4;
    bx[tid][0] = bp[0]; bx[tid][1] = bp[1]; bx[tid][2] = bp[2]; bx[tid][3] = bp[3];
  }
  __syncthreads();

  for (int idx = tid; idx < 1296; idx += 256) {
    int i = idx / 36, j = idx % 36;
    float x1a = bx[i][0], y1a = bx[i][1], x2a = bx[i][2], y2a = bx[i][3];
    float x1b = bx[j][0], y1b = bx[j][1], x2b = bx[j][2], y2b = bx[j][3];
    float areaA = fmaxf(x2a - x1a, 0.f) * fmaxf(y2a - y1a, 0.f);
    float areaB = fmaxf(x2b - x1b, 0.f) * fmaxf(y2b - y1b, 0.f);
    float iw = fmaxf(fminf(x2a, x2b) - fmaxf(x1a, x1b), 0.f);
    float ih = fmaxf(fminf(y2a, y2b) - fmaxf(y1a, y1b), 0.f);
    float inter = iw * ih;
    float iou = inter / (areaA + areaB - inter + 1e-12f);
    float dd = 1.f - iou;
    float rel = att[i] * att[j];
    dist[i][j] = dd;
    scr[i][j]  = plin_f(plw_s[0], plc_s[0], rel) * plin_f(plw_s[1], plc_s[1], dd);
    ds2[i][j]  = plin_f(plw_s[3], plc_s[3], rel) * plin_f(plw_s[4], plc_s[4], dd);
  }
  __syncthreads();

  for (int idx = tid; idx < 1296; idx += 256) {
    int b = idx / 36, c = idx % 36;
    float p = plin_f(plw_s[2], plc_s[2], 1.f - fabsf(att[b] - att[c]));
    for (int a = 0; a < 36; ++a)
      p *= plin_f(plw_s[2], plc_s[2], 1.f - fabsf(ds2[a][b] - ds2[a][c]));
    sim[b][c] = p;
  }
  __syncthreads();

  if (tid < 36) {
    float s = 0.f;
    for (int c = 0; c < 36; ++c) s += sim[tid][c];
    rs[tid] = s;
  }
  __syncthreads();

  float p1 = 0.f, p4 = 0.f;
  for (int idx = tid; idx < 1296; idx += 256) {
    int b = idx / 36, c = idx % 36;
    p1 += scr[b][c] / (rs[b] * rs[c]);
    p4 += fabsf(plin_f(plw_s[6], plc_s[6], dist[b][c]) - 0.5f);
  }
  float p2 = 0.f, p3 = 0.f;
  if (tid < 36) {
    p2 = plin_f(plw_s[0], plc_s[0], att[tid]*att[tid]) / rs[tid];
    p3 = fabsf(plin_f(plw_s[5], plc_s[5], att[tid]) - 0.5f);
  }
  float s1 = breduce(p1, red, tid);
  float s2 = breduce(p2, red, tid);
  float s3 = breduce(p3, red, tid);
  float s4 = breduce(p4, red, tid);

  if (tid == 0) {
    float total = sqrtf(s1 + s2 + 1e-20f);
    float cf = plin_f(plw_s[7], plc_s[7], s3 * (1.f/36.f) + s4 * (1.f/1296.f));
    float sc = fminf(fmaxf(total, 0.f), 36.f);
    float fl = floorf(sc);
    int ii = (int)fl; if (ii > 36) ii = 36;
    b_f = sc - fl;
    b_i = ii;
    b_cf = cf;
    conf_out[n] = cf;
  }
  __syncthreads();
  if (tid < 37) {
    int ii = b_i;
    int ir = (ii + 1 > 36) ? 36 : ii + 1;
    float v = ((tid == ii) ? (1.f - b_f) : 0.f) + ((tid == ir) ? b_f : 0.f);
    pred[(size_t)n*37 + tid] = v * b_cf;
  }
}

// ---------------------------------------------------------------------------
extern "C" void kernel_launch(void* const* d_in, const int* in_sizes, int n_in,
                              void* d_out, int out_size, void* d_ws, size_t ws_size,
                              hipStream_t stream) {
  const float* v_emb = (const float*)d_in[0];
  const float* q_emb = (const float*)d_in[1];
  const float* boxes = (const float*)d_in[2];
  const float* Wq    = (const float*)d_in[3];
  const float* bq    = (const float*)d_in[4];
  const float* Wk    = (const float*)d_in[5];
  const float* bk    = (const float*)d_in[6];
  const float* Wv    = (const float*)d_in[7];
  const float* bv    = (const float*)d_in[8];
  const float* in_w  = (const float*)d_in[9];
  const float* in_b  = (const float*)d_in[10];
  const float* out_w = (const float*)d_in[11];
  const float* out_b = (const float*)d_in[12];
  const float* ln_g  = (const float*)d_in[13];
  const float* ln_b  = (const float*)d_in[14];
  const float* l0_w  = (const float*)d_in[15];
  const float* l0_b  = (const float*)d_in[16];
  const float* l1_w  = (const float*)d_in[17];
  const float* l1_b  = (const float*)d_in[18];
  const float* lo_w  = (const float*)d_in[19];
  const float* lo_b  = (const float*)d_in[20];
  const float* pw    = (const float*)d_in[21];

  float* ws = (float*)d_ws;
  // persistent fp32 region
  float* plw   = ws + 0;        // 136 (reserve 256)
  float* plc   = ws + 256;      // 136 (reserve 256)
  float* cbuf  = ws + 512;      // 768
  float* x1    = ws + 1280;     // 614400 -> 615680
  // persistent f16 region (element offsets within hb)
  f16* hb = (f16*)(ws + 615680);
  f16* A_hi    = hb + 0;         // 768*256 = 196608
  f16* A_lo    = hb + 196608;
  f16* outw_hi = hb + 393216;    // 256*256 = 65536
  f16* outw_lo = hb + 458752;
  f16* l0w_hi  = hb + 524288;    // 640*256 = 163840
  f16* l0w_lo  = hb + 688128;
  f16* l1w_hi  = hb + 851968;    // 640*256 = 163840
  f16* l1w_lo  = hb + 1015808;
  f16* qp_hi   = hb + 1179648;   // 1024*256 = 262144
  f16* qp_lo   = hb + 1441792;
  f16* v_hi    = hb + 1703936;   // 102400*256 = 26214400
  f16* v_lo    = hb + 27918336;  // end 54132736 f16 = 27066368 float slots
  const size_t small_floats = 615680 + 27066368;   // 27,682,048 floats (~111 MB)

  // per-image chunk cost (floats):
  //   qkv 76800 + mlb partials 2000 (100 rows x 10 float2) + 4x12800 f16 halves
  //   = 130000
  size_t avail = (ws_size / 4 > small_floats) ? (ws_size / 4 - small_floats) : 0;
  int NC = 1024;
  while (NC > 32 && (size_t)NC * 130000ull > avail) NC >>= 1;

  float* qkv_c = ws + small_floats;                   // NC*76800
  float2* part = (float2*)(qkv_c + (size_t)NC * 76800); // NC*1000 float2 = NC*2000 floats
  f16* ao_hi  = (f16*)((float*)(void*)part + (size_t)NC * 2000);
  f16* ao_lo  = ao_hi + (size_t)NC * 25600;
  f16* int_hi = ao_lo + (size_t)NC * 25600;
  f16* int_lo = int_hi + (size_t)NC * 25600;

  float* out    = (float*)d_out;
  float* scores = out;             // N*R
  float* pred   = out + 102400;    // N*37
  float* conf   = out + 140288;    // N

  prep_plin<<<1, 64, 0, stream>>>(pw, plw, plc);
  fuse_c<<<3, 256, 0, stream>>>(in_w, in_b, bq, bk, bv, cbuf);
  fuse_A<<<768, 256, 0, stream>>>(in_w, Wq, Wk, Wv, A_hi, A_lo);
  split_vec<<<(65536/4 + 255)/256, 256, 0, stream>>>(out_w, outw_hi, outw_lo, 65536/4);
  conv_w600<<<640, 256, 0, stream>>>(l0_w, l0w_hi, l0w_lo);
  conv_w600<<<640, 256, 0, stream>>>(l1_w, l1w_hi, l1w_lo);
  split_vec<<<(26214400/4 + 255)/256, 256, 0, stream>>>(v_emb, v_hi, v_lo, 26214400/4);
  pool_split<<<N_, 256, 0, stream>>>(q_emb, qp_hi, qp_lo);
  {
    dim3 gx(1024/128, 5);   // x1 = q_pool @ l1_w^T + l1_b  (M=1024, Opad=640)
    gemm_f16s<true><<<gx, 256, 0, stream>>>(qp_hi, qp_lo, l1w_hi, l1w_lo,
                                            l1_b, x1, 600);
  }

  for (int n0 = 0; n0 < N_; n0 += NC) {
    const int M = NC * 100;
    const size_t voff = (size_t)n0 * 100 * 256;

    dim3 g1(M / 128, 6);   // O=768
    gemm_f16s<false><<<g1, 256, 0, stream>>>(v_hi + voff, v_lo + voff,
                                             A_hi, A_lo, cbuf, qkv_c, 768);

    attn_mfma<<<NC * H_, 512, 0, stream>>>(qkv_c, ao_hi, ao_lo);

    // out-proj + fused LayerNorm -> split f16
    gemm2_ln<<<M / 128, 256, 0, stream>>>(ao_hi, ao_lo, outw_hi, outw_lo,
                                          out_b, ln_g, ln_b, int_hi, int_lo);

    // l0 GEMM + fused MLB partial reduction (x0 never materialized)
    dim3 g3(M / 128, 5);   // Opad=640
    gemm_l0_mlb<<<g3, 256, 0, stream>>>(int_hi, int_lo, l0w_hi, l0w_lo,
                                        l0_b, x1 + (size_t)n0 * 600, lo_w, part);

    mlb_reduce<<<(M + 255)/256, 256, 0, stream>>>(part, lo_b,
                                                  scores + (size_t)n0 * 100, M);
  }

  counter_kernel<<<N_, 256, 0, stream>>>(scores, boxes, plw, plc, pred, conf);
}

// Round 6
// 809.341 us; speedup vs baseline: 1.2424x; 1.0897x over previous
//
#include <hip/hip_runtime.h>

// Problem constants
#define N_   1024
#define R_   100
#define D_   256
#define T_   14
#define H_   8
#define DH_  32
#define MM_  600
#define OBJ_ 36

typedef _Float16 f16;
typedef __attribute__((ext_vector_type(8))) _Float16 f16x8;
typedef __attribute__((ext_vector_type(4))) _Float16 f16x4v;
typedef __attribute__((ext_vector_type(4))) float f32x4;

// fp32 -> (hi, lo) fp16 split: x ≈ hi + lo with ~22-bit combined mantissa
__device__ __forceinline__ void f2h_split(float x, f16& hi, f16& lo) {
  hi = (_Float16)x;
  lo = (_Float16)(x - (float)hi);
}

// async 16B global->LDS
#define GL16(gp, lp) __builtin_amdgcn_global_load_lds( \
    (const __attribute__((address_space(1))) void*)(gp), \
    (__attribute__((address_space(3))) void*)(lp), 16, 0, 0)

// XCD-aware remap: co-locate all gridDim.y variants of one x-panel on one XCD
// (consecutive slots) so the shared X-panel is fetched into that XCD's L2 once.
// Bijective when gridDim.x % 8 == 0; identity otherwise. Perf-only.
__device__ __forceinline__ void xcd_remap(int& bx, int& by) {
  int nx = gridDim.x, ny = gridDim.y;
  if ((nx & 7) == 0) {
    int id = bx + nx * by;
    int xcd = id & 7, slot = id >> 3;
    bx = xcd + 8 * (slot / ny);
    by = slot % ny;
  }
}

// ---------------------------------------------------------------------------
__device__ __forceinline__ float plin_f(const float* __restrict__ w,
                                        const float* __restrict__ cs, float x) {
  float xc = fminf(fmaxf(x, 0.f), 1.f);
  float y  = 16.f * xc;
  float fy = floorf(y);
  int   i  = (int)fy;              // 0..16
  float f  = y - fy;
  int   ip = i + 1; if (ip > 16) ip = 16;
  return cs[i] + f * w[ip];
}

// ---------------------------------------------------------------------------
__global__ void prep_plin(const float* __restrict__ pw, float* __restrict__ plw,
                          float* __restrict__ plc) {
  int p = threadIdx.x;
  if (p < 8) {
    float w[17];
    float sum = 0.f;
    w[0] = 0.f;
    for (int k = 1; k < 17; ++k) { w[k] = fabsf(pw[p*17 + k]); sum += w[k]; }
    float inv = 1.f / sum;
    float c = 0.f;
    for (int k = 0; k < 17; ++k) {
      float wk = w[k] * inv;
      c += wk;
      plw[p*17 + k] = wk;
      plc[p*17 + k] = c;
    }
  }
}

// ---------------------------------------------------------------------------
__global__ void fuse_c(const float* __restrict__ in_w, const float* __restrict__ in_b,
                       const float* __restrict__ bq, const float* __restrict__ bk,
                       const float* __restrict__ bv, float* __restrict__ c) {
  int i = blockIdx.x * blockDim.x + threadIdx.x;
  if (i < 768) {
    const float* bsel = (i < 256) ? bq : ((i < 512) ? bk : bv);
    float acc = in_b[i];
    for (int o = 0; o < 256; ++o) acc += in_w[(size_t)i*256 + o] * bsel[o];
    c[i] = acc;
  }
}

__global__ __launch_bounds__(256) void fuse_A(const float* __restrict__ in_w,
    const float* __restrict__ Wq, const float* __restrict__ Wk,
    const float* __restrict__ Wv, f16* __restrict__ Ahi, f16* __restrict__ Alo) {
  int i = blockIdx.x;        // 0..767
  int j = threadIdx.x;       // 0..255
  const float* Wsel = (i < 256) ? Wq : ((i < 512) ? Wk : Wv);
  __shared__ float row[256];
  row[j] = in_w[(size_t)i*256 + j];
  __syncthreads();
  float acc = 0.f;
  for (int o = 0; o < 256; ++o) acc += row[o] * Wsel[(size_t)o*256 + j];
  f16 h, l; f2h_split(acc, h, l);
  Ahi[(size_t)i*256 + j] = h;
  Alo[(size_t)i*256 + j] = l;
}

__global__ __launch_bounds__(256) void split_vec(const float* __restrict__ in,
    f16* __restrict__ hi, f16* __restrict__ lo, int n4) {
  int i = blockIdx.x * blockDim.x + threadIdx.x;
  if (i < n4) {
    float4 v = ((const float4*)in)[i];
    union { f16 h[4]; ushort4 u; } H, L;
    f2h_split(v.x, H.h[0], L.h[0]);
    f2h_split(v.y, H.h[1], L.h[1]);
    f2h_split(v.z, H.h[2], L.h[2]);
    f2h_split(v.w, H.h[3], L.h[3]);
    ((ushort4*)hi)[i] = H.u;
    ((ushort4*)lo)[i] = L.u;
  }
}

// 600x256 weight -> split fp16 padded to 640x256 (zero rows beyond 600)
__global__ __launch_bounds__(256) void conv_w600(const float* __restrict__ w,
    f16* __restrict__ hi, f16* __restrict__ lo) {
  int o = blockIdx.x;        // 0..639
  int j = threadIdx.x;       // 0..255
  f16 h = (f16)0.f, l = (f16)0.f;
  if (o < 600) f2h_split(w[(size_t)o*256 + j], h, l);
  hi[(size_t)o*256 + j] = h;
  lo[(size_t)o*256 + j] = l;
}

// q_emb mean-pool -> split fp16 (one block per n)
__global__ __launch_bounds__(256) void pool_split(const float* __restrict__ q_emb,
    f16* __restrict__ qph, f16* __restrict__ qpl) {
  int n = blockIdx.x, tid = threadIdx.x;
  float s = 0.f;
  for (int t = 0; t < 14; ++t) s += q_emb[((size_t)n*14 + t)*256 + tid];
  s *= (1.f/14.f);
  f16 h, l; f2h_split(s, h, l);
  qph[(size_t)n*256 + tid] = h;
  qpl[(size_t)n*256 + tid] = l;
}

// ---------------------------------------------------------------------------
// split-fp16 MFMA GEMM (fp32-accurate): C[m][o] = sum_k X[m][k]*W[o][k] + bias[o]
template<bool BOUND>
__global__ __launch_bounds__(256) void gemm_f16s(
    const f16* __restrict__ Xhi, const f16* __restrict__ Xlo,
    const f16* __restrict__ Whi, const f16* __restrict__ Wlo,
    const float* __restrict__ bias, float* __restrict__ C, int Oreal) {
  __shared__ f16 XsH[128 * 32];
  __shared__ f16 XsL[128 * 32];
  __shared__ f16 WsH[128 * 32];
  __shared__ f16 WsL[128 * 32];
  const int tid  = threadIdx.x;
  const int wave = tid >> 6, lane = tid & 63;
  int bx = blockIdx.x, by = blockIdx.y;
  xcd_remap(bx, by);
  const int bm = bx * 128, bn = by * 128;
  const int wm = (wave & 1) * 64, wn = (wave >> 1) * 64;
  const int col = lane & 15, quad = lane >> 4;

  const int s = wave * 64 + lane;
  const int r0 = s >> 2,         cseg = (s & 3) * 8;
  const int r1 = (s + 256) >> 2;
  const size_t o0 = (size_t)(bm + r0) * 256 + cseg;
  const size_t o1 = (size_t)(bm + r1) * 256 + cseg;
  const size_t p0 = (size_t)(bn + r0) * 256 + cseg;
  const size_t p1 = (size_t)(bn + r1) * 256 + cseg;
  char* XHB = (char*)XsH + wave * 1024;
  char* XLB = (char*)XsL + wave * 1024;
  char* WHB = (char*)WsH + wave * 1024;
  char* WLB = (char*)WsL + wave * 1024;

  f32x4 acc[4][4] = {};

  for (int k0 = 0; k0 < 256; k0 += 32) {
    GL16(Xhi + o0 + k0, XHB);
    GL16(Xhi + o1 + k0, XHB + 4096);
    GL16(Xlo + o0 + k0, XLB);
    GL16(Xlo + o1 + k0, XLB + 4096);
    GL16(Whi + p0 + k0, WHB);
    GL16(Whi + p1 + k0, WHB + 4096);
    GL16(Wlo + p0 + k0, WLB);
    GL16(Wlo + p1 + k0, WLB + 4096);
    __syncthreads();

    f16x8 ah[4], al[4], bh[4], bl[4];
#pragma unroll
    for (int i = 0; i < 4; ++i) {
      int ro = (wm + i*16 + col) * 32 + quad * 8;
      ah[i] = *(const f16x8*)(XsH + ro);
      al[i] = *(const f16x8*)(XsL + ro);
    }
#pragma unroll
    for (int j = 0; j < 4; ++j) {
      int ro = (wn + j*16 + col) * 32 + quad * 8;
      bh[j] = *(const f16x8*)(WsH + ro);
      bl[j] = *(const f16x8*)(WsL + ro);
    }
#pragma unroll
    for (int i = 0; i < 4; ++i)
#pragma unroll
      for (int j = 0; j < 4; ++j) {
        acc[i][j] = __builtin_amdgcn_mfma_f32_16x16x32_f16(al[i], bh[j], acc[i][j], 0, 0, 0);
        acc[i][j] = __builtin_amdgcn_mfma_f32_16x16x32_f16(ah[i], bl[j], acc[i][j], 0, 0, 0);
        acc[i][j] = __builtin_amdgcn_mfma_f32_16x16x32_f16(ah[i], bh[j], acc[i][j], 0, 0, 0);
      }
    __syncthreads();
  }

#pragma unroll
  for (int j = 0; j < 4; ++j) {
    int o = bn + wn + j*16 + col;
    if (BOUND && o >= Oreal) continue;
    float bo = bias[o];
#pragma unroll
    for (int i = 0; i < 4; ++i) {
#pragma unroll
      for (int r = 0; r < 4; ++r) {
        int m = bm + wm + i*16 + quad*4 + r;
        C[(size_t)m * Oreal + o] = acc[i][j][r] + bo;
      }
    }
  }
}

// ---------------------------------------------------------------------------
// l0 GEMM with FUSED MLB partial reduction v3 (register x1, 32KB LDS).
__global__ __launch_bounds__(256) void gemm_l0_mlb(
    const f16* __restrict__ Xhi, const f16* __restrict__ Xlo,
    const f16* __restrict__ Whi, const f16* __restrict__ Wlo,
    const float* __restrict__ bias, const float* __restrict__ x1,
    const float* __restrict__ lo_w, float2* __restrict__ part) {
  __shared__ f16 XsH[128 * 32];
  __shared__ f16 XsL[128 * 32];
  __shared__ f16 WsH[128 * 32];
  __shared__ f16 WsL[128 * 32];
  const int tid  = threadIdx.x;
  const int wave = tid >> 6, lane = tid & 63;
  int bx = blockIdx.x, by = blockIdx.y;
  xcd_remap(bx, by);
  const int bm = bx * 128, bn = by * 128;
  const int wm = (wave & 1) * 64, wn = (wave >> 1) * 64;
  const int col = lane & 15, quad = lane >> 4;

  const int s = wave * 64 + lane;
  const int r0 = s >> 2,         cseg = (s & 3) * 8;
  const int r1 = (s + 256) >> 2;
  const size_t o0 = (size_t)(bm + r0) * 256 + cseg;
  const size_t o1 = (size_t)(bm + r1) * 256 + cseg;
  const size_t p0 = (size_t)(bn + r0) * 256 + cseg;
  const size_t p1 = (size_t)(bn + r1) * 256 + cseg;
  char* XHB = (char*)XsH + wave * 1024;
  char* XLB = (char*)XsL + wave * 1024;
  char* WHB = (char*)WsH + wave * 1024;
  char* WLB = (char*)WsL + wave * 1024;

  f32x4 acc[4][4] = {};

  for (int k0 = 0; k0 < 256; k0 += 32) {
    GL16(Xhi + o0 + k0, XHB);
    GL16(Xhi + o1 + k0, XHB + 4096);
    GL16(Xlo + o0 + k0, XLB);
    GL16(Xlo + o1 + k0, XLB + 4096);
    GL16(Whi + p0 + k0, WHB);
    GL16(Whi + p1 + k0, WHB + 4096);
    GL16(Wlo + p0 + k0, WLB);
    GL16(Wlo + p1 + k0, WLB + 4096);
    __syncthreads();

    f16x8 ah[4], al[4], bh[4], bl[4];
#pragma unroll
    for (int i = 0; i < 4; ++i) {
      int ro = (wm + i*16 + col) * 32 + quad * 8;
      ah[i] = *(const f16x8*)(XsH + ro);
      al[i] = *(const f16x8*)(XsL + ro);
    }
#pragma unroll
    for (int j = 0; j < 4; ++j) {
      int ro = (wn + j*16 + col) * 32 + quad * 8;
      bh[j] = *(const f16x8*)(WsH + ro);
      bl[j] = *(const f16x8*)(WsL + ro);
    }
#pragma unroll
    for (int i = 0; i < 4; ++i)
#pragma unroll
      for (int j = 0; j < 4; ++j) {
        acc[i][j] = __builtin_amdgcn_mfma_f32_16x16x32_f16(al[i], bh[j], acc[i][j], 0, 0, 0);
        acc[i][j] = __builtin_amdgcn_mfma_f32_16x16x32_f16(ah[i], bl[j], acc[i][j], 0, 0, 0);
        acc[i][j] = __builtin_amdgcn_mfma_f32_16x16x32_f16(ah[i], bh[j], acc[i][j], 0, 0, 0);
      }
    __syncthreads();
  }

  // ---- fused MLB epilogue v3 ----
  const int M = (int)gridDim.x * 128;        // chunk rows (== NC*100)
  const int NCimg = M / 100;
  const int mA = bm + wm;                    // first row of this wave's tile
  const int imgA = mA / 100;
  int imgB = imgA + 1; if (imgB > NCimg - 1) imgB = NCimg - 1;
  const int rB = (imgA + 1) * 100;           // first row belonging to imgB

  float bo4[4], lw4[4], x1A[4], x1B[4];
#pragma unroll
  for (int j = 0; j < 4; ++j) {
    int o = bn + wn + j*16 + col;
    bool v = (o < 600);
    bo4[j] = v ? bias[o] : 0.f;
    lw4[j] = v ? lo_w[o] : 0.f;
    x1A[j] = v ? x1[(size_t)imgA*600 + o] : 0.f;
    x1B[j] = v ? x1[(size_t)imgB*600 + o] : 0.f;
  }

#pragma unroll
  for (int i = 0; i < 4; ++i) {
#pragma unroll
    for (int rr = 0; rr < 4; ++rr) {
      int m = bm + wm + i*16 + quad*4 + rr;
      bool hiImg = (m >= rB);
      float ss = 0.f, dt = 0.f;
#pragma unroll
      for (int j = 0; j < 4; ++j) {
        float xv = hiImg ? x1B[j] : x1A[j];
        float v = (acc[i][j][rr] + bo4[j]) * xv;
        float av = fabsf(v);
        ss += av;                             // rt*rt == |v|
        dt += copysignf(sqrtf(av), v) * lw4[j];
      }
#pragma unroll
      for (int msk = 1; msk < 16; msk <<= 1) {
        ss += __shfl_xor(ss, msk, 64);
        dt += __shfl_xor(dt, msk, 64);
      }
      if (col == 0) {
        float2 pv; pv.x = ss; pv.y = dt;
        part[(size_t)m * 10 + by * 2 + (wn >> 6)] = pv;
      }
    }
  }
}

// combine 10 partials per row -> normalize -> sigmoid -> scores
__global__ __launch_bounds__(256) void mlb_reduce(const float2* __restrict__ part,
    const float* __restrict__ lo_b, float* __restrict__ out, int M) {
  int m = blockIdx.x * 256 + threadIdx.x;
  if (m < M) {
    const float2* p = part + (size_t)m * 10;
    float ss = 0.f, dt = 0.f;
#pragma unroll
    for (int t = 0; t < 10; ++t) { float2 v = p[t]; ss += v.x; dt += v.y; }
    float sc = dt / fmaxf(sqrtf(ss), 1e-12f) + lo_b[0];
    out[m] = 1.f / (1.f + __expf(-sc));
  }
}

// ---------------------------------------------------------------------------
// out-proj GEMM + fused LayerNorm: tile 128 rows x FULL 256 cols per block.
__global__ __launch_bounds__(256) void gemm2_ln(
    const f16* __restrict__ Xhi, const f16* __restrict__ Xlo,
    const f16* __restrict__ Whi, const f16* __restrict__ Wlo,
    const float* __restrict__ bias, const float* __restrict__ g,
    const float* __restrict__ b, f16* __restrict__ ohi, f16* __restrict__ olo) {
  __shared__ f16 XsH[128 * 32];
  __shared__ f16 XsL[128 * 32];
  __shared__ f16 WsH[256 * 32];
  __shared__ f16 WsL[256 * 32];
  __shared__ float gbb[768];   // g | b | bias
  const int tid  = threadIdx.x;
  const int wave = tid >> 6, lane = tid & 63;
  const int bm = blockIdx.x * 128;
  const int wm = wave * 32;
  const int col16 = lane & 15, quad = lane >> 4;

  for (int i = tid; i < 768; i += 256)
    gbb[i] = (i < 256) ? g[i] : ((i < 512) ? b[i - 256] : bias[i - 512]);

  const int s = wave * 64 + lane;
  const int rx0 = s >> 2, cseg = (s & 3) * 8;
  const int rx1 = (s + 256) >> 2;
  const size_t o0 = (size_t)(bm + rx0) * 256 + cseg;
  const size_t o1 = (size_t)(bm + rx1) * 256 + cseg;
  char* XHB = (char*)XsH + wave * 1024;
  char* XLB = (char*)XsL + wave * 1024;

  f32x4 acc[2][16] = {};

  for (int k0 = 0; k0 < 256; k0 += 32) {
    GL16(Xhi + o0 + k0, XHB);
    GL16(Xhi + o1 + k0, XHB + 4096);
    GL16(Xlo + o0 + k0, XLB);
    GL16(Xlo + o1 + k0, XLB + 4096);
#pragma unroll
    for (int is = 0; is < 4; ++is) {
      int sw = is * 256 + s;
      size_t wo = (size_t)(sw >> 2) * 256 + (sw & 3) * 8 + k0;
      GL16(Whi + wo, (char*)WsH + is * 4096 + wave * 1024);
      GL16(Wlo + wo, (char*)WsL + is * 4096 + wave * 1024);
    }
    __syncthreads();

    f16x8 ah[2], al[2];
#pragma unroll
    for (int i = 0; i < 2; ++i) {
      int ro = (wm + i*16 + col16) * 32 + quad * 8;
      ah[i] = *(const f16x8*)(XsH + ro);
      al[i] = *(const f16x8*)(XsL + ro);
    }
#pragma unroll
    for (int j = 0; j < 16; ++j) {
      int ro = (j*16 + col16) * 32 + quad * 8;
      f16x8 bh = *(const f16x8*)(WsH + ro);
      f16x8 bl = *(const f16x8*)(WsL + ro);
#pragma unroll
      for (int i = 0; i < 2; ++i) {
        acc[i][j] = __builtin_amdgcn_mfma_f32_16x16x32_f16(al[i], bh, acc[i][j], 0, 0, 0);
        acc[i][j] = __builtin_amdgcn_mfma_f32_16x16x32_f16(ah[i], bl, acc[i][j], 0, 0, 0);
        acc[i][j] = __builtin_amdgcn_mfma_f32_16x16x32_f16(ah[i], bh, acc[i][j], 0, 0, 0);
      }
    }
    __syncthreads();
  }

#pragma unroll
  for (int i = 0; i < 2; ++i) {
#pragma unroll
    for (int r = 0; r < 4; ++r) {
      float x[16];
      float sum = 0.f;
#pragma unroll
      for (int j = 0; j < 16; ++j) {
        float v = acc[i][j][r] + gbb[512 + j*16 + col16];
        x[j] = v;
        sum += v;
      }
#pragma unroll
      for (int msk = 1; msk < 16; msk <<= 1) sum += __shfl_xor(sum, msk, 64);
      float mu = sum * (1.f/256.f);
      float s2 = 0.f;
#pragma unroll
      for (int j = 0; j < 16; ++j) { float d = x[j] - mu; s2 += d * d; }
#pragma unroll
      for (int msk = 1; msk < 16; msk <<= 1) s2 += __shfl_xor(s2, msk, 64);
      float inv = rsqrtf(s2 * (1.f/256.f) + 1e-5f);
      size_t m = (size_t)(bm + wm + i*16 + quad*4 + r);
#pragma unroll
      for (int j = 0; j < 16; ++j) {
        int col = j*16 + col16;
        float yv = (x[j] - mu) * inv * gbb[col] + gbb[256 + col];
        f16 hh, ll; f2h_split(yv, hh, ll);
        ohi[m*256 + col] = hh;
        olo[m*256 + col] = ll;
      }
    }
  }
}

// ---------------------------------------------------------------------------
// FUSED qkv-projection + MFMA attention. One block per (local n, head).
// Phase 0 (GEMM): qkv head-slice = X[112x256] @ A_head[96x256]^T + bias,
//   X/W tiles staged via global_load_lds (8 k-steps of 32), split-f16 MFMA.
//   Output C-layout: lane(col16=o_col, quad*4+r=m_row), acc[6] = q0 q1 k0 k1 v0 v1.
// Epilogue: K/V split-f16 -> LDS tiles (same layouts as before); q -> packed
//   u32 XOR-swizzled per-wave scratch (aliased on P32, dead until phase 2).
// Phase 1-3: identical register-softmax attention as before.
__global__ __launch_bounds__(512, 4) void attn_fused(
    const f16* __restrict__ v_hi, const f16* __restrict__ v_lo,
    const f16* __restrict__ A_hi, const f16* __restrict__ A_lo,
    const float* __restrict__ cbuf,
    f16* __restrict__ aohi, f16* __restrict__ aolo) {
  // XCD-bijective map: all 8 heads of an image on one XCD (share X-panel).
  int b = blockIdx.x;
  const int nper = (int)(gridDim.x >> 6);          // NC/8
  const int n = (b & 7) * nper + (b >> 6);
  const int h = (b >> 3) & 7;

  __shared__ f16 KH[112*32], KL[112*32];      // K rows (split)       14,336 B
  __shared__ f16 VTH[32*116], VTL[32*116];    // V^T (split), s=116   14,848 B
  __shared__ unsigned int P32[112*116];       // packed P hi|lo       51,968 B
  // aliases into P32 (dead until phase 2):
  char* STG = (char*)P32;                      // staging: 26,624 B
  f16* XsH = (f16*)STG;                        // [112][32]
  f16* XsL = XsH + 3584;
  f16* WsH = XsH + 7168;                       // [96][32]
  f16* WsL = XsH + 10240;
  unsigned int* qsc32 = (unsigned int*)(STG + 37632);  // 7 waves x 512 u32

  const int tid = threadIdx.x;
  const int wave = tid >> 6, lane = tid & 63;
  const int col16 = lane & 15, quad = lane >> 4;
  const float scale = 0.17677669529663687f;   // 1/sqrt(32)
  const int tm = wave;                        // row tile owned by this wave

  // bias regs (q0 q1 k0 k1 v0 v1): o_local = j*16+col16 in [0,96)
  float bo[6];
#pragma unroll
  for (int j = 0; j < 6; ++j) {
    int ol = j*16 + col16;
    bo[j] = cbuf[(ol >> 5)*256 + h*32 + (ol & 31)];
  }

  // ---- phase 0: GEMM over K=256 in 8 steps of 32 ----
  f32x4 acc[6] = {};
  for (int k0 = 0; k0 < 256; k0 += 32) {
    // stage X (112x32, clamp rows>99 to 99) and W (96 head rows of A)
#pragma unroll
    for (int jj = 0; jj < 4; ++jj) {
      int c = tid + jj*512;
      if (c >= 1664) break;                 // wave-uniform (regions 64-aligned)
      const f16* src;
      if (c < 896) {
        int cc = (c < 448) ? c : c - 448;
        int r = cc >> 2; if (r > 99) r = 99;
        const f16* vb = (c < 448) ? v_hi : v_lo;
        src = vb + ((size_t)n*100 + r)*256 + k0 + (cc & 3)*8;
      } else {
        int cc = (c < 1280) ? c - 896 : c - 1280;
        int row = cc >> 2;
        int o = ((row >> 5) << 8) + h*32 + (row & 31);
        const f16* ab = (c < 1280) ? A_hi : A_lo;
        src = ab + (size_t)o*256 + k0 + (cc & 3)*8;
      }
      GL16(src, STG + (size_t)(c - lane)*16);
    }
    __syncthreads();
    if (tm < 7) {
      int ro = (tm*16 + col16)*32 + quad*8;
      f16x8 ah = *(const f16x8*)(XsH + ro);
      f16x8 al = *(const f16x8*)(XsL + ro);
#pragma unroll
      for (int j = 0; j < 6; ++j) {
        int wo = (j*16 + col16)*32 + quad*8;
        f16x8 bh = *(const f16x8*)(WsH + wo);
        f16x8 bl = *(const f16x8*)(WsL + wo);
        acc[j] = __builtin_amdgcn_mfma_f32_16x16x32_f16(al, bh, acc[j], 0, 0, 0);
        acc[j] = __builtin_amdgcn_mfma_f32_16x16x32_f16(ah, bl, acc[j], 0, 0, 0);
        acc[j] = __builtin_amdgcn_mfma_f32_16x16x32_f16(ah, bh, acc[j], 0, 0, 0);
      }
    }
    __syncthreads();
  }

  // ---- epilogue: bias + write K/V to LDS tiles, q to swizzled scratch ----
  if (tm < 7) {
#pragma unroll
    for (int j = 0; j < 2; ++j) {
#pragma unroll
      for (int r = 0; r < 4; ++r) {
        int key = tm*16 + quad*4 + r;
        int d = j*16 + col16;
        f16 hh, ll;
        f2h_split(acc[2+j][r] + bo[2+j], hh, ll);   // K
        KH[key*32 + d] = hh; KL[key*32 + d] = ll;
        f2h_split(acc[4+j][r] + bo[4+j], hh, ll);   // V (transposed store)
        VTH[d*116 + key] = hh; VTL[d*116 + key] = ll;
        f2h_split((acc[j][r] + bo[j]) * scale, hh, ll);  // q (scaled)
        union { struct { f16 h, l; } f; unsigned int u; } pk;
        pk.f.h = hh; pk.f.l = ll;
        int mrow = quad*4 + r;
        qsc32[wave*512 + mrow*32 + (d ^ (r << 3))] = pk.u;
      }
    }
  }
  __syncthreads();   // K/V/q visible to all waves

  // q A-frags from scratch (own wave region); then barrier before P32 writes
  f16x8 ah = {}, al = {};
  if (tm < 7) {
    int sw = (col16 & 3) << 3;
    const unsigned int* qp = qsc32 + wave*512 + col16*32 + ((quad*8) ^ sw);
    f16x8 e0 = *(const f16x8*)(qp);
    f16x8 e1 = *(const f16x8*)(qp + 4);
    ah = __builtin_shufflevector(e0, e1, 0, 2, 4, 6, 8, 10, 12, 14);
    al = __builtin_shufflevector(e0, e1, 1, 3, 5, 7, 9, 11, 13, 15);
  }
  __syncthreads();   // all q-scratch reads done before P32 (aliased) is written

  if (tm < 7) {
    // ---- phase 1: S row-tile in registers -> register softmax -> packed P
    f32x4 sacc[7];
#pragma unroll
    for (int tn = 0; tn < 7; ++tn) {
      int off = (tn*16 + col16)*32 + quad*8;
      f16x8 bh = *(const f16x8*)(KH + off);
      f16x8 bl = *(const f16x8*)(KL + off);
      f32x4 a = {};
      a = __builtin_amdgcn_mfma_f32_16x16x32_f16(al, bh, a, 0, 0, 0);
      a = __builtin_amdgcn_mfma_f32_16x16x32_f16(ah, bl, a, 0, 0, 0);
      a = __builtin_amdgcn_mfma_f32_16x16x32_f16(ah, bh, a, 0, 0, 0);
      sacc[tn] = a;
    }
    // mask cols >= 100
    if (col16 >= 4) {
      sacc[6][0] = -1e30f; sacc[6][1] = -1e30f;
      sacc[6][2] = -1e30f; sacc[6][3] = -1e30f;
    }
    float mx[4];
#pragma unroll
    for (int r = 0; r < 4; ++r) {
      float mv = sacc[0][r];
#pragma unroll
      for (int tn = 1; tn < 7; ++tn) mv = fmaxf(mv, sacc[tn][r]);
      mx[r] = mv;
    }
#pragma unroll
    for (int msk = 1; msk < 16; msk <<= 1)
#pragma unroll
      for (int r = 0; r < 4; ++r) mx[r] = fmaxf(mx[r], __shfl_xor(mx[r], msk, 64));
    float sm[4] = {0.f, 0.f, 0.f, 0.f};
#pragma unroll
    for (int tn = 0; tn < 7; ++tn)
#pragma unroll
      for (int r = 0; r < 4; ++r) {
        float p = __expf(sacc[tn][r] - mx[r]);
        sacc[tn][r] = p;
        sm[r] += p;
      }
#pragma unroll
    for (int msk = 1; msk < 16; msk <<= 1)
#pragma unroll
      for (int r = 0; r < 4; ++r) sm[r] += __shfl_xor(sm[r], msk, 64);
    float inv[4];
#pragma unroll
    for (int r = 0; r < 4; ++r) inv[r] = 1.f / sm[r];
#pragma unroll
    for (int tn = 0; tn < 7; ++tn)
#pragma unroll
      for (int r = 0; r < 4; ++r) {
        float p = sacc[tn][r] * inv[r];
        f16 hh, ll; f2h_split(p, hh, ll);
        union { struct { f16 h, l; } f; unsigned int u; } pk;
        pk.f.h = hh; pk.f.l = ll;
        P32[(tm*16 + quad*4 + r)*116 + tn*16 + col16] = pk.u;
      }

    // ---- phase 3: O = P V (same-wave P reads)
    f16x8 vh[2][4], vl[2][4];
#pragma unroll
    for (int td = 0; td < 2; ++td)
#pragma unroll
      for (int kc = 0; kc < 4; ++kc) {
        if (kc == 3 && quad >= 2) {
          f16x8 z = {};
          vh[td][kc] = z; vl[td][kc] = z;
        } else {
          int off = (td*16 + col16)*116 + kc*32 + quad*8;
          f16x4v h0 = *(const f16x4v*)(VTH + off);
          f16x4v h1 = *(const f16x4v*)(VTH + off + 4);
          f16x4v l0 = *(const f16x4v*)(VTL + off);
          f16x4v l1 = *(const f16x4v*)(VTL + off + 4);
          f16x8 hv, lv;
#pragma unroll
          for (int t = 0; t < 4; ++t) { hv[t] = h0[t]; hv[t+4] = h1[t]; lv[t] = l0[t]; lv[t+4] = l1[t]; }
          vh[td][kc] = hv; vl[td][kc] = lv;
        }
      }
    f32x4 oacc[2] = {};
#pragma unroll
    for (int kc = 0; kc < 4; ++kc) {
      f16x8 ph, pl;
      if (kc == 3 && quad >= 2) {
        f16x8 z = {};
        ph = z; pl = z;
      } else {
        const unsigned int* pp = P32 + (tm*16 + col16)*116 + kc*32 + quad*8;
        f16x8 e0 = *(const f16x8*)(pp);
        f16x8 e1 = *(const f16x8*)(pp + 4);
        ph = __builtin_shufflevector(e0, e1, 0, 2, 4, 6, 8, 10, 12, 14);
        pl = __builtin_shufflevector(e0, e1, 1, 3, 5, 7, 9, 11, 13, 15);
      }
#pragma unroll
      for (int td = 0; td < 2; ++td) {
        oacc[td] = __builtin_amdgcn_mfma_f32_16x16x32_f16(pl, vh[td][kc], oacc[td], 0, 0, 0);
        oacc[td] = __builtin_amdgcn_mfma_f32_16x16x32_f16(ph, vl[td][kc], oacc[td], 0, 0, 0);
        oacc[td] = __builtin_amdgcn_mfma_f32_16x16x32_f16(ph, vh[td][kc], oacc[td], 0, 0, 0);
      }
    }
#pragma unroll
    for (int td = 0; td < 2; ++td) {
#pragma unroll
      for (int r = 0; r < 4; ++r) {
        int m = tm*16 + quad*4 + r;
        if (m < 100) {
          size_t oidx = ((size_t)n*100 + m)*256 + h*32 + td*16 + col16;
          f16 hh, ll; f2h_split(oacc[td][r], hh, ll);
          aohi[oidx] = hh;
          aolo[oidx] = ll;
        }
      }
    }
  }
}

// ---------------------------------------------------------------------------
__device__ __forceinline__ float breduce(float v, float* red, int tid) {
  for (int o = 32; o > 0; o >>= 1) v += __shfl_down(v, o, 64);
  if ((tid & 63) == 0) red[tid >> 6] = v;
  __syncthreads();
  float r = red[0] + red[1] + red[2] + red[3];
  __syncthreads();
  return r;
}

// counting module: one block per n (global)
__global__ __launch_bounds__(256) void counter_kernel(
    const float* __restrict__ scores, const float* __restrict__ boxes,
    const float* __restrict__ plw, const float* __restrict__ plc,
    float* __restrict__ pred, float* __restrict__ conf_out) {
  int n = blockIdx.x, tid = threadIdx.x;
  __shared__ float plw_s[8][17], plc_s[8][17];
  __shared__ float sval[128];
  __shared__ int   sidx[128];
  __shared__ float att[36], bx[36][4];
  __shared__ float dist[36][36], scr[36][36], ds2[36][36], sim[36][36];
  __shared__ float rs[36];
  __shared__ float red[4];
  __shared__ float b_f, b_cf;
  __shared__ int   b_i;

  for (int i = tid; i < 136; i += 256) {
    (&plw_s[0][0])[i] = plw[i];
    (&plc_s[0][0])[i] = plc[i];
  }
  if (tid < 128) {
    sval[tid] = (tid < 100) ? scores[(size_t)n*100 + tid] : -1e30f;
    sidx[tid] = tid;
  }
  __syncthreads();

  for (int k = 2; k <= 128; k <<= 1) {
    for (int j = k >> 1; j > 0; j >>= 1) {
      if (tid < 128) {
        int ixj = tid ^ j;
        if (ixj > tid) {
          float va = sval[tid], vb = sval[ixj];
          int   ia = sidx[tid], ib = sidx[ixj];
          bool a_before_b = (va > vb) || (va == vb && ia < ib);
          bool ascending = ((tid & k) == 0);
          bool doswap = ascending ? !a_before_b : a_before_b;
          if (doswap) { sval[tid] = vb; sval[ixj] = va; sidx[tid] = ib; sidx[ixj] = ia; }
        }
      }
      __syncthreads();
    }
  }

  if (tid < 36) {
    att[tid] = sval[tid];
    const float* bp = boxes + ((size_t)n*100 + sidx[tid])*4;
    bx[tid][0] = bp[0]; bx[tid][1] = bp[1]; bx[tid][2] = bp[2]; bx[tid][3] = bp[3];
  }
  __syncthreads();

  for (int idx = tid; idx < 1296; idx += 256) {
    int i = idx / 36, j = idx % 36;
    float x1a = bx[i][0], y1a = bx[i][1], x2a = bx[i][2], y2a = bx[i][3];
    float x1b = bx[j][0], y1b = bx[j][1], x2b = bx[j][2], y2b = bx[j][3];
    float areaA = fmaxf(x2a - x1a, 0.f) * fmaxf(y2a - y1a, 0.f);
    float areaB = fmaxf(x2b - x1b, 0.f) * fmaxf(y2b - y1b, 0.f);
    float iw = fmaxf(fminf(x2a, x2b) - fmaxf(x1a, x1b), 0.f);
    float ih = fmaxf(fminf(y2a, y2b) - fmaxf(y1a, y1b), 0.f);
    float inter = iw * ih;
    float iou = inter / (areaA + areaB - inter + 1e-12f);
    float dd = 1.f - iou;
    float rel = att[i] * att[j];
    dist[i][j] = dd;
    scr[i][j]  = plin_f(plw_s[0], plc_s[0], rel) * plin_f(plw_s[1], plc_s[1], dd);
    ds2[i][j]  = plin_f(plw_s[3], plc_s[3], rel) * plin_f(plw_s[4], plc_s[4], dd);
  }
  __syncthreads();

  for (int idx = tid; idx < 1296; idx += 256) {
    int b = idx / 36, c = idx % 36;
    float p = plin_f(plw_s[2], plc_s[2], 1.f - fabsf(att[b] - att[c]));
    for (int a = 0; a < 36; ++a)
      p *= plin_f(plw_s[2], plc_s[2], 1.f - fabsf(ds2[a][b] - ds2[a][c]));
    sim[b][c] = p;
  }
  __syncthreads();

  if (tid < 36) {
    float s = 0.f;
    for (int c = 0; c < 36; ++c) s += sim[tid][c];
    rs[tid] = s;
  }
  __syncthreads();

  float p1 = 0.f, p4 = 0.f;
  for (int idx = tid; idx < 1296; idx += 256) {
    int b = idx / 36, c = idx % 36;
    p1 += scr[b][c] / (rs[b] * rs[c]);
    p4 += fabsf(plin_f(plw_s[6], plc_s[6], dist[b][c]) - 0.5f);
  }
  float p2 = 0.f, p3 = 0.f;
  if (tid < 36) {
    p2 = plin_f(plw_s[0], plc_s[0], att[tid]*att[tid]) / rs[tid];
    p3 = fabsf(plin_f(plw_s[5], plc_s[5], att[tid]) - 0.5f);
  }
  float s1 = breduce(p1, red, tid);
  float s2 = breduce(p2, red, tid);
  float s3 = breduce(p3, red, tid);
  float s4 = breduce(p4, red, tid);

  if (tid == 0) {
    float total = sqrtf(s1 + s2 + 1e-20f);
    float cf = plin_f(plw_s[7], plc_s[7], s3 * (1.f/36.f) + s4 * (1.f/1296.f));
    float sc = fminf(fmaxf(total, 0.f), 36.f);
    float fl = floorf(sc);
    int ii = (int)fl; if (ii > 36) ii = 36;
    b_f = sc - fl;
    b_i = ii;
    b_cf = cf;
    conf_out[n] = cf;
  }
  __syncthreads();
  if (tid < 37) {
    int ii = b_i;
    int ir = (ii + 1 > 36) ? 36 : ii + 1;
    float v = ((tid == ii) ? (1.f - b_f) : 0.f) + ((tid == ir) ? b_f : 0.f);
    pred[(size_t)n*37 + tid] = v * b_cf;
  }
}

// ---------------------------------------------------------------------------
extern "C" void kernel_launch(void* const* d_in, const int* in_sizes, int n_in,
                              void* d_out, int out_size, void* d_ws, size_t ws_size,
                              hipStream_t stream) {
  const float* v_emb = (const float*)d_in[0];
  const float* q_emb = (const float*)d_in[1];
  const float* boxes = (const float*)d_in[2];
  const float* Wq    = (const float*)d_in[3];
  const float* bq    = (const float*)d_in[4];
  const float* Wk    = (const float*)d_in[5];
  const float* bk    = (const float*)d_in[6];
  const float* Wv    = (const float*)d_in[7];
  const float* bv    = (const float*)d_in[8];
  const float* in_w  = (const float*)d_in[9];
  const float* in_b  = (const float*)d_in[10];
  const float* out_w = (const float*)d_in[11];
  const float* out_b = (const float*)d_in[12];
  const float* ln_g  = (const float*)d_in[13];
  const float* ln_b  = (const float*)d_in[14];
  const float* l0_w  = (const float*)d_in[15];
  const float* l0_b  = (const float*)d_in[16];
  const float* l1_w  = (const float*)d_in[17];
  const float* l1_b  = (const float*)d_in[18];
  const float* lo_w  = (const float*)d_in[19];
  const float* lo_b  = (const float*)d_in[20];
  const float* pw    = (const float*)d_in[21];

  float* ws = (float*)d_ws;
  float* plw   = ws + 0;        // 136 (reserve 256)
  float* plc   = ws + 256;
  float* cbuf  = ws + 512;      // 768
  float* x1    = ws + 1280;     // 614400 -> 615680
  f16* hb = (f16*)(ws + 615680);
  f16* A_hi    = hb + 0;         // 768*256
  f16* A_lo    = hb + 196608;
  f16* outw_hi = hb + 393216;    // 256*256
  f16* outw_lo = hb + 458752;
  f16* l0w_hi  = hb + 524288;    // 640*256
  f16* l0w_lo  = hb + 688128;
  f16* l1w_hi  = hb + 851968;    // 640*256
  f16* l1w_lo  = hb + 1015808;
  f16* qp_hi   = hb + 1179648;   // 1024*256
  f16* qp_lo   = hb + 1441792;
  f16* v_hi    = hb + 1703936;   // 102400*256
  f16* v_lo    = hb + 27918336;
  const size_t small_floats = 615680 + 27066368;   // ~111 MB

  // per-image chunk cost (floats): part 2000 + 4x12800 f16 halves = 53,200
  size_t avail = (ws_size / 4 > small_floats) ? (ws_size / 4 - small_floats) : 0;
  int NC = 1024;
  while (NC > 32 && (size_t)NC * 53200ull > avail) NC >>= 1;

  float2* part = (float2*)(ws + small_floats);        // NC*1000 float2
  f16* ao_hi  = (f16*)((float*)(void*)part + (size_t)NC * 2000);
  f16* ao_lo  = ao_hi + (size_t)NC * 25600;
  f16* int_hi = ao_lo + (size_t)NC * 25600;
  f16* int_lo = int_hi + (size_t)NC * 25600;

  float* out    = (float*)d_out;
  float* scores = out;             // N*R
  float* pred   = out + 102400;    // N*37
  float* conf   = out + 140288;    // N

  prep_plin<<<1, 64, 0, stream>>>(pw, plw, plc);
  fuse_c<<<3, 256, 0, stream>>>(in_w, in_b, bq, bk, bv, cbuf);
  fuse_A<<<768, 256, 0, stream>>>(in_w, Wq, Wk, Wv, A_hi, A_lo);
  split_vec<<<(65536/4 + 255)/256, 256, 0, stream>>>(out_w, outw_hi, outw_lo, 65536/4);
  conv_w600<<<640, 256, 0, stream>>>(l0_w, l0w_hi, l0w_lo);
  conv_w600<<<640, 256, 0, stream>>>(l1_w, l1w_hi, l1w_lo);
  split_vec<<<(26214400/4 + 255)/256, 256, 0, stream>>>(v_emb, v_hi, v_lo, 26214400/4);
  pool_split<<<N_, 256, 0, stream>>>(q_emb, qp_hi, qp_lo);
  {
    dim3 gx(1024/128, 5);   // x1 = q_pool @ l1_w^T + l1_b
    gemm_f16s<true><<<gx, 256, 0, stream>>>(qp_hi, qp_lo, l1w_hi, l1w_lo,
                                            l1_b, x1, 600);
  }

  for (int n0 = 0; n0 < N_; n0 += NC) {
    const int M = NC * 100;
    const size_t voff = (size_t)n0 * 100 * 256;

    // fused qkv-projection + attention (qkv never materialized)
    attn_fused<<<NC * H_, 512, 0, stream>>>(v_hi + voff, v_lo + voff,
                                            A_hi, A_lo, cbuf, ao_hi, ao_lo);

    // out-proj + fused LayerNorm -> split f16
    gemm2_ln<<<M / 128, 256, 0, stream>>>(ao_hi, ao_lo, outw_hi, outw_lo,
                                          out_b, ln_g, ln_b, int_hi, int_lo);

    // l0 GEMM + fused MLB partial reduction (x0 never materialized)
    dim3 g3(M / 128, 5);   // Opad=640
    gemm_l0_mlb<<<g3, 256, 0, stream>>>(int_hi, int_lo, l0w_hi, l0w_lo,
                                        l0_b, x1 + (size_t)n0 * 600, lo_w, part);

    mlb_reduce<<<(M + 255)/256, 256, 0, stream>>>(part, lo_b,
                                                  scores + (size_t)n0 * 100, M);
  }

  counter_kernel<<<N_, 256, 0, stream>>>(scores, boxes, plw, plc, pred, conf);
}